// Round 1
// baseline (599.730 us; speedup 1.0000x reference)
//
#include <hip/hip_runtime.h>
#include <hip/hip_bf16.h>
#include <math.h>

#define DMODEL 1024
#define LSEQ   2048
#define BATCH  2
#define NHEADS 16
#define DHEAD  64
#define DFF    4096
#define MROWS  (BATCH*LSEQ)   // 4096

typedef __attribute__((ext_vector_type(8))) short short8;
typedef __attribute__((ext_vector_type(4))) float f32x4;
using bf16 = __hip_bfloat16;

static __device__ __forceinline__ f32x4 mfma16(short8 a, short8 b, f32x4 c) {
    return __builtin_amdgcn_mfma_f32_16x16x32_bf16(a, b, c, 0, 0, 0);
}

// ---------------- fp32 -> bf16 conversion ----------------
__global__ void f2b_kernel(const float* __restrict__ in, bf16* __restrict__ out, int n4) {
    int i = blockIdx.x * blockDim.x + threadIdx.x;
    if (i >= n4) return;
    float4 v = reinterpret_cast<const float4*>(in)[i];
    union { ushort4 u; bf16 h[4]; } o;
    o.h[0] = __float2bfloat16(v.x);
    o.h[1] = __float2bfloat16(v.y);
    o.h[2] = __float2bfloat16(v.z);
    o.h[3] = __float2bfloat16(v.w);
    reinterpret_cast<ushort4*>(out)[i] = o.u;
}

// ---------------- residual add ----------------
__global__ void add_kernel(const float* __restrict__ a, const float* __restrict__ b,
                           float* __restrict__ o, int n4) {
    int i = blockIdx.x * blockDim.x + threadIdx.x;
    if (i >= n4) return;
    float4 x = reinterpret_cast<const float4*>(a)[i];
    float4 y = reinterpret_cast<const float4*>(b)[i];
    float4 z; z.x = x.x + y.x; z.y = x.y + y.y; z.z = x.z + y.z; z.w = x.w + y.w;
    reinterpret_cast<float4*>(o)[i] = z;
}

// ---------------- GEMM: C[M,N] = A[M,K] (bf16) @ W[N,K]^T (bf16) + bias ----------------
// EPI: 0 = fp32 store, 1 = exact-GELU + bf16 store, 2 = bf16 store
template<int EPI>
__global__ __launch_bounds__(256) void gemm_bt(const bf16* __restrict__ A,
                                               const bf16* __restrict__ W,
                                               const float* __restrict__ bias,
                                               void* __restrict__ Cout,
                                               int M, int N, int K) {
    __shared__ bf16 As[128][40];   // pad 40 bf16 = 80B rows -> conflict-free frag reads
    __shared__ bf16 Ws[128][40];
    const int t    = threadIdx.x;
    const int m0   = blockIdx.x * 128;
    const int n0   = blockIdx.y * 128;
    const int wave = t >> 6, lane = t & 63;
    const int wr   = (wave >> 1) * 64;   // wave row offset within tile
    const int wc   = (wave & 1) * 64;    // wave col offset
    const int lr   = lane & 15, lkb = lane >> 4;
    const int srow = t >> 2, scol = (t & 3) * 8;

    f32x4 acc[4][4];
#pragma unroll
    for (int i = 0; i < 4; ++i)
#pragma unroll
        for (int j = 0; j < 4; ++j)
            acc[i][j] = (f32x4){0.f, 0.f, 0.f, 0.f};

    for (int k0 = 0; k0 < K; k0 += 32) {
        // stage A and W tiles: 128 rows x 32 cols bf16 each
#pragma unroll
        for (int p = 0; p < 2; ++p) {
            int r = srow + p * 64;
            *reinterpret_cast<uint4*>(&As[r][scol]) =
                *reinterpret_cast<const uint4*>(&A[(size_t)(m0 + r) * K + k0 + scol]);
            *reinterpret_cast<uint4*>(&Ws[r][scol]) =
                *reinterpret_cast<const uint4*>(&W[(size_t)(n0 + r) * K + k0 + scol]);
        }
        __syncthreads();
        short8 a[4], b[4];
#pragma unroll
        for (int i = 0; i < 4; ++i)
            a[i] = *reinterpret_cast<const short8*>(&As[wr + i * 16 + lr][lkb * 8]);
#pragma unroll
        for (int j = 0; j < 4; ++j)
            b[j] = *reinterpret_cast<const short8*>(&Ws[wc + j * 16 + lr][lkb * 8]);
#pragma unroll
        for (int i = 0; i < 4; ++i)
#pragma unroll
            for (int j = 0; j < 4; ++j)
                acc[i][j] = mfma16(a[i], b[j], acc[i][j]);
        __syncthreads();
    }

    // epilogue: C/D layout col=lane&15, row=(lane>>4)*4+reg  [verified mapping]
#pragma unroll
    for (int i = 0; i < 4; ++i) {
#pragma unroll
        for (int j = 0; j < 4; ++j) {
            int col = n0 + wc + j * 16 + lr;
            float bsv = bias[col];
#pragma unroll
            for (int q = 0; q < 4; ++q) {
                int row = m0 + wr + i * 16 + lkb * 4 + q;
                float v = acc[i][j][q] + bsv;
                if (EPI == 0) {
                    reinterpret_cast<float*>(Cout)[(size_t)row * N + col] = v;
                } else if (EPI == 1) {
                    float gv = 0.5f * v * (1.0f + erff(v * 0.70710678118654752f));
                    reinterpret_cast<bf16*>(Cout)[(size_t)row * N + col] = __float2bfloat16(gv);
                } else {
                    reinterpret_cast<bf16*>(Cout)[(size_t)row * N + col] = __float2bfloat16(v);
                }
            }
        }
    }
}

// ---------------- fused attention (flash-style, bf16 MFMA) ----------------
// grid: (L/64 q-tiles, B*H); block 256 threads (4 waves, 16 q-rows each)
__global__ __launch_bounds__(256) void attn_kernel(const bf16* __restrict__ Q,
                                                   const bf16* __restrict__ Km,
                                                   const bf16* __restrict__ V,
                                                   bf16* __restrict__ O) {
    __shared__ bf16 Qs[64][72];
    __shared__ bf16 Ks[64][72];
    __shared__ bf16 VsT[64][72];   // transposed V tile: VsT[d][m]
    __shared__ bf16 Ps[64][72];
    const int t    = threadIdx.x;
    const int wave = t >> 6, lane = t & 63;
    const int lr   = lane & 15, lkb = lane >> 4;
    const int q0   = blockIdx.x * 64;
    const int b    = blockIdx.y >> 4, h = blockIdx.y & 15;
    const size_t base = (size_t)b * LSEQ * DMODEL + (size_t)h * DHEAD;

    // stage Q tile (64x64 bf16), once
#pragma unroll
    for (int p = 0; p < 2; ++p) {
        int idx = t + p * 256;
        int row = idx >> 3, c = (idx & 7) * 8;
        *reinterpret_cast<uint4*>(&Qs[row][c]) =
            *reinterpret_cast<const uint4*>(&Q[base + (size_t)(q0 + row) * DMODEL + c]);
    }
    __syncthreads();
    short8 qa[2];
    qa[0] = *reinterpret_cast<const short8*>(&Qs[wave * 16 + lr][lkb * 8]);
    qa[1] = *reinterpret_cast<const short8*>(&Qs[wave * 16 + lr][32 + lkb * 8]);

    f32x4 o[4];
#pragma unroll
    for (int dj = 0; dj < 4; ++dj) o[dj] = (f32x4){0.f, 0.f, 0.f, 0.f};
    float mrun[4], lrun[4];
#pragma unroll
    for (int q = 0; q < 4; ++q) { mrun[q] = -1e30f; lrun[q] = 0.f; }

    for (int kt = 0; kt < LSEQ / 64; ++kt) {
        const int k0 = kt * 64;
        __syncthreads();   // protect Ks/VsT read in previous iteration
#pragma unroll
        for (int p = 0; p < 2; ++p) {
            int idx = t + p * 256;
            int row = idx >> 3, c = (idx & 7) * 8;
            *reinterpret_cast<uint4*>(&Ks[row][c]) =
                *reinterpret_cast<const uint4*>(&Km[base + (size_t)(k0 + row) * DMODEL + c]);
            union { uint4 u; bf16 hh[8]; } tv;
            tv.u = *reinterpret_cast<const uint4*>(&V[base + (size_t)(k0 + row) * DMODEL + c]);
#pragma unroll
            for (int e = 0; e < 8; ++e) VsT[c + e][row] = tv.hh[e];
        }
        __syncthreads();

        // S = Q K^T for this wave's 16 q-rows x 64 keys
        f32x4 s[4];
#pragma unroll
        for (int j = 0; j < 4; ++j) {
            short8 kb0 = *reinterpret_cast<const short8*>(&Ks[j * 16 + lr][lkb * 8]);
            short8 kb1 = *reinterpret_cast<const short8*>(&Ks[j * 16 + lr][32 + lkb * 8]);
            f32x4 z = (f32x4){0.f, 0.f, 0.f, 0.f};
            z = mfma16(qa[0], kb0, z);
            z = mfma16(qa[1], kb1, z);
            s[j] = z;
        }
        // scale + time bias, row max
        float mx[4];
#pragma unroll
        for (int q = 0; q < 4; ++q) mx[q] = -1e30f;
#pragma unroll
        for (int j = 0; j < 4; ++j) {
            int cm = k0 + j * 16 + lr;
#pragma unroll
            for (int q = 0; q < 4; ++q) {
                int rq = q0 + wave * 16 + lkb * 4 + q;
                float sv = s[j][q] * 0.125f - 0.1f * fabsf((float)(rq - cm));
                s[j][q] = sv;
                mx[q] = fmaxf(mx[q], sv);
            }
        }
#pragma unroll
        for (int q = 0; q < 4; ++q) {
#pragma unroll
            for (int off = 1; off < 16; off <<= 1)
                mx[q] = fmaxf(mx[q], __shfl_xor(mx[q], off));
        }
        float alpha[4];
#pragma unroll
        for (int q = 0; q < 4; ++q) {
            float mnew = fmaxf(mrun[q], mx[q]);
            alpha[q] = __expf(mrun[q] - mnew);
            mrun[q] = mnew;
        }
        float rs[4] = {0.f, 0.f, 0.f, 0.f};
#pragma unroll
        for (int j = 0; j < 4; ++j) {
#pragma unroll
            for (int q = 0; q < 4; ++q) {
                float p = __expf(s[j][q] - mrun[q]);
                rs[q] += p;
                Ps[wave * 16 + lkb * 4 + q][j * 16 + lr] = __float2bfloat16(p);
            }
        }
#pragma unroll
        for (int q = 0; q < 4; ++q) {
#pragma unroll
            for (int off = 1; off < 16; off <<= 1)
                rs[q] += __shfl_xor(rs[q], off);
            lrun[q] = lrun[q] * alpha[q] + rs[q];
        }
#pragma unroll
        for (int dj = 0; dj < 4; ++dj)
#pragma unroll
            for (int q = 0; q < 4; ++q) o[dj][q] *= alpha[q];
        __syncthreads();   // Ps writes visible (conservative)

        short8 pa0 = *reinterpret_cast<const short8*>(&Ps[wave * 16 + lr][lkb * 8]);
        short8 pa1 = *reinterpret_cast<const short8*>(&Ps[wave * 16 + lr][32 + lkb * 8]);
#pragma unroll
        for (int dj = 0; dj < 4; ++dj) {
            short8 vb0 = *reinterpret_cast<const short8*>(&VsT[dj * 16 + lr][lkb * 8]);
            short8 vb1 = *reinterpret_cast<const short8*>(&VsT[dj * 16 + lr][32 + lkb * 8]);
            o[dj] = mfma16(pa0, vb0, o[dj]);
            o[dj] = mfma16(pa1, vb1, o[dj]);
        }
    }

    // epilogue: normalize and store bf16
#pragma unroll
    for (int dj = 0; dj < 4; ++dj) {
#pragma unroll
        for (int q = 0; q < 4; ++q) {
            int row = q0 + wave * 16 + lkb * 4 + q;
            int col = dj * 16 + lr;
            float val = o[dj][q] / lrun[q];
            O[base + (size_t)row * DMODEL + col] = __float2bfloat16(val);
        }
    }
}

// ---------------- moving average (k=25, zero-pad, /25) + LayerNorm ----------------
// one block per (b,l) row; 256 threads x 4 cols
__global__ __launch_bounds__(256) void mavg_ln_kernel(const float* __restrict__ r,
                                                      const float* __restrict__ g,
                                                      const float* __restrict__ be,
                                                      float* __restrict__ out,
                                                      bf16* __restrict__ outb) {
    const int row = blockIdx.x;
    const int b = row >> 11, l = row & 2047;
    const int t = threadIdx.x, c = t * 4;
    const float* base = r + (size_t)b * LSEQ * DMODEL;
    int j0 = l - 12; if (j0 < 0) j0 = 0;
    int j1 = l + 12; if (j1 > LSEQ - 1) j1 = LSEQ - 1;
    float s0 = 0.f, s1 = 0.f, s2 = 0.f, s3 = 0.f;
    for (int j = j0; j <= j1; ++j) {
        float4 v = *reinterpret_cast<const float4*>(&base[(size_t)j * DMODEL + c]);
        s0 += v.x; s1 += v.y; s2 += v.z; s3 += v.w;
    }
    const float kinv = 1.0f / 25.0f;
    float t0 = s0 * kinv, t1 = s1 * kinv, t2 = s2 * kinv, t3 = s3 * kinv;
    float p1 = t0 + t1 + t2 + t3;
    float p2 = t0 * t0 + t1 * t1 + t2 * t2 + t3 * t3;
    const int lane = t & 63, wv = t >> 6;
#pragma unroll
    for (int off = 1; off < 64; off <<= 1) {
        p1 += __shfl_xor(p1, off);
        p2 += __shfl_xor(p2, off);
    }
    __shared__ float red[8];
    if (lane == 0) { red[wv] = p1; red[4 + wv] = p2; }
    __syncthreads();
    p1 = red[0] + red[1] + red[2] + red[3];
    p2 = red[4] + red[5] + red[6] + red[7];
    const float mu  = p1 * (1.0f / 1024.0f);
    const float var = p2 * (1.0f / 1024.0f) - mu * mu;
    const float inv = rsqrtf(var + 1e-5f);
    float4 gg = *reinterpret_cast<const float4*>(&g[c]);
    float4 bb = *reinterpret_cast<const float4*>(&be[c]);
    float o0 = (t0 - mu) * inv * gg.x + bb.x;
    float o1 = (t1 - mu) * inv * gg.y + bb.y;
    float o2 = (t2 - mu) * inv * gg.z + bb.z;
    float o3 = (t3 - mu) * inv * gg.w + bb.w;
    float4 ov; ov.x = o0; ov.y = o1; ov.z = o2; ov.w = o3;
    *reinterpret_cast<float4*>(&out[(size_t)row * DMODEL + c]) = ov;
    if (outb) {
        union { ushort4 u; bf16 hh[4]; } ob;
        ob.hh[0] = __float2bfloat16(o0);
        ob.hh[1] = __float2bfloat16(o1);
        ob.hh[2] = __float2bfloat16(o2);
        ob.hh[3] = __float2bfloat16(o3);
        reinterpret_cast<ushort4*>(outb + (size_t)row * DMODEL)[t] = ob.u;
    }
}

extern "C" void kernel_launch(void* const* d_in, const int* in_sizes, int n_in,
                              void* d_out, int out_size, void* d_ws, size_t ws_size,
                              hipStream_t stream) {
    const float* x   = (const float*)d_in[0];
    const float* Wq  = (const float*)d_in[1];
    const float* bq  = (const float*)d_in[2];
    const float* Wk  = (const float*)d_in[3];
    const float* bk  = (const float*)d_in[4];
    const float* Wv  = (const float*)d_in[5];
    const float* bv  = (const float*)d_in[6];
    const float* Wo  = (const float*)d_in[7];
    const float* bo  = (const float*)d_in[8];
    const float* W1  = (const float*)d_in[9];
    const float* b1  = (const float*)d_in[10];
    const float* W2  = (const float*)d_in[11];
    const float* b2  = (const float*)d_in[12];
    const float* g1  = (const float*)d_in[13];
    const float* be1 = (const float*)d_in[14];
    const float* g2  = (const float*)d_in[15];
    const float* be2 = (const float*)d_in[16];
    float* out = (float*)d_out;
    char* ws = (char*)d_ws;
    const size_t MB = 1u << 20;

    bf16* xb  = (bf16*)(ws + 0);        //  8MB
    bf16* qb  = (bf16*)(ws + 8  * MB);  //  8MB
    bf16* kb  = (bf16*)(ws + 16 * MB);  //  8MB
    bf16* vb  = (bf16*)(ws + 24 * MB);  //  8MB
    bf16* aob = (bf16*)(ws + 32 * MB);  //  8MB
    bf16* Wqb = (bf16*)(ws + 40 * MB);  //  2MB
    bf16* Wkb = (bf16*)(ws + 42 * MB);
    bf16* Wvb = (bf16*)(ws + 44 * MB);
    bf16* Wob = (bf16*)(ws + 46 * MB);
    bf16* W1b = (bf16*)(ws + 48 * MB);  //  8MB
    bf16* W2b = (bf16*)(ws + 56 * MB);  //  8MB
    float* y  = (float*)(ws + 64 * MB); // 16MB (Wo out, then FF2 out)
    float* rr = (float*)(ws + 80 * MB); // 16MB residual tmp
    float* a  = (float*)(ws + 96 * MB); // 16MB LN1 out fp32
    bf16* ab  = (bf16*)(ws + 112 * MB); //  8MB LN1 out bf16
    bf16* hb  = (bf16*)(ws + 120 * MB); // 32MB FF hidden bf16 -> ends at 152MB

    // dtype conversions
    f2b_kernel<<<(MROWS * DMODEL / 4) / 256, 256, 0, stream>>>(x, xb, MROWS * DMODEL / 4);
    f2b_kernel<<<(DMODEL * DMODEL / 4) / 256, 256, 0, stream>>>(Wq, Wqb, DMODEL * DMODEL / 4);
    f2b_kernel<<<(DMODEL * DMODEL / 4) / 256, 256, 0, stream>>>(Wk, Wkb, DMODEL * DMODEL / 4);
    f2b_kernel<<<(DMODEL * DMODEL / 4) / 256, 256, 0, stream>>>(Wv, Wvb, DMODEL * DMODEL / 4);
    f2b_kernel<<<(DMODEL * DMODEL / 4) / 256, 256, 0, stream>>>(Wo, Wob, DMODEL * DMODEL / 4);
    f2b_kernel<<<(DFF * DMODEL / 4) / 256, 256, 0, stream>>>(W1, W1b, DFF * DMODEL / 4);
    f2b_kernel<<<(DFF * DMODEL / 4) / 256, 256, 0, stream>>>(W2, W2b, DFF * DMODEL / 4);

    dim3 blk(256);
    // QKV projections (bf16 out)
    gemm_bt<2><<<dim3(32, 8), blk, 0, stream>>>(xb, Wqb, bq, qb, MROWS, DMODEL, DMODEL);
    gemm_bt<2><<<dim3(32, 8), blk, 0, stream>>>(xb, Wkb, bk, kb, MROWS, DMODEL, DMODEL);
    gemm_bt<2><<<dim3(32, 8), blk, 0, stream>>>(xb, Wvb, bv, vb, MROWS, DMODEL, DMODEL);
    // attention
    attn_kernel<<<dim3(32, 32), blk, 0, stream>>>(qb, kb, vb, aob);
    // output projection (fp32 out)
    gemm_bt<0><<<dim3(32, 8), blk, 0, stream>>>(aob, Wob, bo, y, MROWS, DMODEL, DMODEL);
    // residual + movavg + LN1 (fp32 out a, bf16 out ab)
    add_kernel<<<(MROWS * DMODEL / 4) / 256, 256, 0, stream>>>(x, y, rr, MROWS * DMODEL / 4);
    mavg_ln_kernel<<<MROWS, blk, 0, stream>>>(rr, g1, be1, a, ab);
    // FFN
    gemm_bt<1><<<dim3(32, 32), blk, 0, stream>>>(ab, W1b, b1, hb, MROWS, DFF, DMODEL);
    gemm_bt<0><<<dim3(32, 8), blk, 0, stream>>>(hb, W2b, b2, y, MROWS, DMODEL, DFF);
    // residual + movavg + LN2 -> out
    add_kernel<<<(MROWS * DMODEL / 4) / 256, 256, 0, stream>>>(a, y, rr, MROWS * DMODEL / 4);
    mavg_ln_kernel<<<MROWS, blk, 0, stream>>>(rr, g2, be2, out, nullptr);
}

// Round 2
// 431.147 us; speedup vs baseline: 1.3910x; 1.3910x over previous
//
#include <hip/hip_runtime.h>
#include <hip/hip_bf16.h>
#include <math.h>

#define DMODEL 1024
#define LSEQ   2048
#define BATCH  2
#define NHEADS 16
#define DHEAD  64
#define DFF    4096
#define MROWS  (BATCH*LSEQ)   // 4096

typedef __attribute__((ext_vector_type(8))) short short8;
typedef __attribute__((ext_vector_type(4))) float f32x4;
using bf16 = __hip_bfloat16;

static __device__ __forceinline__ f32x4 mfma16(short8 a, short8 b, f32x4 c) {
    return __builtin_amdgcn_mfma_f32_16x16x32_bf16(a, b, c, 0, 0, 0);
}

static __device__ __forceinline__ void gload16(const void* g, void* l) {
    __builtin_amdgcn_global_load_lds(
        (const __attribute__((address_space(1))) char*)g,
        (__attribute__((address_space(3))) char*)l, 16, 0, 0);
}

// ---------------- fp32 -> bf16 conversion ----------------
__global__ void f2b_kernel(const float* __restrict__ in, bf16* __restrict__ out, int n4) {
    int i = blockIdx.x * blockDim.x + threadIdx.x;
    if (i >= n4) return;
    float4 v = reinterpret_cast<const float4*>(in)[i];
    union { ushort4 u; bf16 h[4]; } o;
    o.h[0] = __float2bfloat16(v.x);
    o.h[1] = __float2bfloat16(v.y);
    o.h[2] = __float2bfloat16(v.z);
    o.h[3] = __float2bfloat16(v.w);
    reinterpret_cast<ushort4*>(out)[i] = o.u;
}

// ---------------- residual add ----------------
__global__ void add_kernel(const float* __restrict__ a, const float* __restrict__ b,
                           float* __restrict__ o, int n4) {
    int i = blockIdx.x * blockDim.x + threadIdx.x;
    if (i >= n4) return;
    float4 x = reinterpret_cast<const float4*>(a)[i];
    float4 y = reinterpret_cast<const float4*>(b)[i];
    float4 z; z.x = x.x + y.x; z.y = x.y + y.y; z.z = x.z + y.z; z.w = x.w + y.w;
    reinterpret_cast<float4*>(o)[i] = z;
}

// ---------------- bias concat (bq,bk,bv -> 3072) ----------------
__global__ void concat3_kernel(const float* __restrict__ a, const float* __restrict__ b,
                               const float* __restrict__ c, float* __restrict__ o) {
    int i = blockIdx.x * blockDim.x + threadIdx.x;
    if (i < DMODEL) { o[i] = a[i]; o[DMODEL + i] = b[i]; o[2 * DMODEL + i] = c[i]; }
}

// ---------------- GEMM (m97 structure): C[M,N] = A[M,K] @ W[N,K]^T + bias ----------------
// linear LDS + global_load_lds width=16; 128x128 tile, BK=32, 4 waves, 4x4 frags/wave
// EPI: 0 = fp32 store, 1 = exact-GELU + bf16 store, 2 = bf16 store
template<int EPI>
__global__ __launch_bounds__(256) void gemm_bt(const bf16* __restrict__ A,
                                               const bf16* __restrict__ W,
                                               const float* __restrict__ bias,
                                               void* __restrict__ Cout,
                                               int M, int N, int K) {
    __shared__ bf16 As[128 * 32];
    __shared__ bf16 Ws[128 * 32];
    const int t    = threadIdx.x;
    const int m0   = blockIdx.x * 128;
    const int n0   = blockIdx.y * 128;
    const int wave = t >> 6, lane = t & 63;
    const int wr   = (wave >> 1) * 64;
    const int wc   = (wave & 1) * 64;
    const int lr   = lane & 15, lkb = lane >> 4;
    const int srow = t >> 2, scol = (t & 3) * 8;

    const bf16* Ag0 = A + (size_t)(m0 + srow) * K + scol;
    const bf16* Ag1 = A + (size_t)(m0 + 64 + srow) * K + scol;
    const bf16* Wg0 = W + (size_t)(n0 + srow) * K + scol;
    const bf16* Wg1 = W + (size_t)(n0 + 64 + srow) * K + scol;
    bf16* AsW = As + wave * 512;   // wave-uniform LDS base; HW adds lane*16B
    bf16* WsW = Ws + wave * 512;

    f32x4 acc[4][4];
#pragma unroll
    for (int i = 0; i < 4; ++i)
#pragma unroll
        for (int j = 0; j < 4; ++j)
            acc[i][j] = (f32x4){0.f, 0.f, 0.f, 0.f};

    for (int k0 = 0; k0 < K; k0 += 32) {
        gload16(Ag0 + k0, AsW);
        gload16(Ag1 + k0, AsW + 2048);
        gload16(Wg0 + k0, WsW);
        gload16(Wg1 + k0, WsW + 2048);
        __syncthreads();
        short8 a[4], b[4];
#pragma unroll
        for (int i = 0; i < 4; ++i)
            a[i] = *reinterpret_cast<const short8*>(&As[(wr + i * 16 + lr) * 32 + lkb * 8]);
#pragma unroll
        for (int j = 0; j < 4; ++j)
            b[j] = *reinterpret_cast<const short8*>(&Ws[(wc + j * 16 + lr) * 32 + lkb * 8]);
#pragma unroll
        for (int i = 0; i < 4; ++i)
#pragma unroll
            for (int j = 0; j < 4; ++j)
                acc[i][j] = mfma16(a[i], b[j], acc[i][j]);
        __syncthreads();
    }

    // epilogue: C/D layout col=lane&15, row=(lane>>4)*4+reg
#pragma unroll
    for (int i = 0; i < 4; ++i) {
#pragma unroll
        for (int j = 0; j < 4; ++j) {
            int col = n0 + wc + j * 16 + lr;
            float bsv = bias[col];
#pragma unroll
            for (int q = 0; q < 4; ++q) {
                int row = m0 + wr + i * 16 + lkb * 4 + q;
                float v = acc[i][j][q] + bsv;
                if (EPI == 0) {
                    reinterpret_cast<float*>(Cout)[(size_t)row * N + col] = v;
                } else if (EPI == 1) {
                    float gv = 0.5f * v * (1.0f + erff(v * 0.70710678118654752f));
                    reinterpret_cast<bf16*>(Cout)[(size_t)row * N + col] = __float2bfloat16(gv);
                } else {
                    reinterpret_cast<bf16*>(Cout)[(size_t)row * N + col] = __float2bfloat16(v);
                }
            }
        }
    }
}

// ---------------- fused attention (flash-style, bf16 MFMA, banded) ----------------
// time bias -0.1|i-j| decays so fast that keys with |i-j|>256 contribute < 3e-11
// relative -> iterate only K-tiles in [qt-4, qt+4] (9 of 32).
// grid: (L/64 q-tiles, B*H); block 256 threads (4 waves, 16 q-rows each)
__global__ __launch_bounds__(256) void attn_kernel(const bf16* __restrict__ Q,
                                                   const bf16* __restrict__ Km,
                                                   const bf16* __restrict__ V,
                                                   bf16* __restrict__ O,
                                                   int ldq, int ldo) {
    __shared__ bf16 Qs[64][72];
    __shared__ bf16 Ks[64][72];
    __shared__ bf16 VsT[64][72];   // transposed V tile: VsT[d][m]
    __shared__ bf16 Ps[64][72];
    const int t    = threadIdx.x;
    const int wave = t >> 6, lane = t & 63;
    const int lr   = lane & 15, lkb = lane >> 4;
    const int qt   = blockIdx.x;
    const int q0   = qt * 64;
    const int b    = blockIdx.y >> 4, h = blockIdx.y & 15;
    const size_t base  = (size_t)b * LSEQ * ldq + (size_t)h * DHEAD;
    const size_t baseo = (size_t)b * LSEQ * ldo + (size_t)h * DHEAD;

    // stage Q tile (64x64 bf16), once
#pragma unroll
    for (int p = 0; p < 2; ++p) {
        int idx = t + p * 256;
        int row = idx >> 3, c = (idx & 7) * 8;
        *reinterpret_cast<uint4*>(&Qs[row][c]) =
            *reinterpret_cast<const uint4*>(&Q[base + (size_t)(q0 + row) * ldq + c]);
    }
    __syncthreads();
    short8 qa[2];
    qa[0] = *reinterpret_cast<const short8*>(&Qs[wave * 16 + lr][lkb * 8]);
    qa[1] = *reinterpret_cast<const short8*>(&Qs[wave * 16 + lr][32 + lkb * 8]);

    f32x4 o[4];
#pragma unroll
    for (int dj = 0; dj < 4; ++dj) o[dj] = (f32x4){0.f, 0.f, 0.f, 0.f};
    float mrun[4], lrun[4];
#pragma unroll
    for (int q = 0; q < 4; ++q) { mrun[q] = -1e30f; lrun[q] = 0.f; }

    int kt0 = qt - 4; if (kt0 < 0) kt0 = 0;
    int kt1 = qt + 4; if (kt1 > LSEQ / 64 - 1) kt1 = LSEQ / 64 - 1;

    for (int kt = kt0; kt <= kt1; ++kt) {
        const int k0 = kt * 64;
        __syncthreads();   // protect Ks/VsT reads of previous iteration
        // K tile: coalesced row-major stage
#pragma unroll
        for (int p = 0; p < 2; ++p) {
            int idx = t + p * 256;
            int row = idx >> 3, c = (idx & 7) * 8;
            *reinterpret_cast<uint4*>(&Ks[row][c]) =
                *reinterpret_cast<const uint4*>(&Km[base + (size_t)(k0 + row) * ldq + c]);
        }
        // V tile transpose: lane l loads row l (16B chunk), writes wave-uniform
        // LDS row, 64 consecutive 2B cols -> conflict-free
        {
            const int vl = lane, vw = wave;
#pragma unroll
            for (int p = 0; p < 2; ++p) {
                int c = vw * 8 + p * 32;
                union { uint4 u; bf16 hh[8]; } tv;
                tv.u = *reinterpret_cast<const uint4*>(&V[base + (size_t)(k0 + vl) * ldq + c]);
#pragma unroll
                for (int e = 0; e < 8; ++e) VsT[c + e][vl] = tv.hh[e];
            }
        }
        __syncthreads();

        // S = Q K^T for this wave's 16 q-rows x 64 keys
        f32x4 s[4];
#pragma unroll
        for (int j = 0; j < 4; ++j) {
            short8 kb0 = *reinterpret_cast<const short8*>(&Ks[j * 16 + lr][lkb * 8]);
            short8 kb1 = *reinterpret_cast<const short8*>(&Ks[j * 16 + lr][32 + lkb * 8]);
            f32x4 z = (f32x4){0.f, 0.f, 0.f, 0.f};
            z = mfma16(qa[0], kb0, z);
            z = mfma16(qa[1], kb1, z);
            s[j] = z;
        }
        // scale + time bias, row max
        float mx[4];
#pragma unroll
        for (int q = 0; q < 4; ++q) mx[q] = -1e30f;
#pragma unroll
        for (int j = 0; j < 4; ++j) {
            int cm = k0 + j * 16 + lr;
#pragma unroll
            for (int q = 0; q < 4; ++q) {
                int rq = q0 + wave * 16 + lkb * 4 + q;
                float sv = s[j][q] * 0.125f - 0.1f * fabsf((float)(rq - cm));
                s[j][q] = sv;
                mx[q] = fmaxf(mx[q], sv);
            }
        }
#pragma unroll
        for (int q = 0; q < 4; ++q) {
#pragma unroll
            for (int off = 1; off < 16; off <<= 1)
                mx[q] = fmaxf(mx[q], __shfl_xor(mx[q], off));
        }
        float alpha[4];
#pragma unroll
        for (int q = 0; q < 4; ++q) {
            float mnew = fmaxf(mrun[q], mx[q]);
            alpha[q] = __expf(mrun[q] - mnew);
            mrun[q] = mnew;
        }
        float rs[4] = {0.f, 0.f, 0.f, 0.f};
#pragma unroll
        for (int j = 0; j < 4; ++j) {
#pragma unroll
            for (int q = 0; q < 4; ++q) {
                float p = __expf(s[j][q] - mrun[q]);
                rs[q] += p;
                Ps[wave * 16 + lkb * 4 + q][j * 16 + lr] = __float2bfloat16(p);
            }
        }
#pragma unroll
        for (int q = 0; q < 4; ++q) {
#pragma unroll
            for (int off = 1; off < 16; off <<= 1)
                rs[q] += __shfl_xor(rs[q], off);
            lrun[q] = lrun[q] * alpha[q] + rs[q];
        }
#pragma unroll
        for (int dj = 0; dj < 4; ++dj)
#pragma unroll
            for (int q = 0; q < 4; ++q) o[dj][q] *= alpha[q];
        __syncthreads();   // Ps visibility (conservative; wave-local in practice)

        short8 pa0 = *reinterpret_cast<const short8*>(&Ps[wave * 16 + lr][lkb * 8]);
        short8 pa1 = *reinterpret_cast<const short8*>(&Ps[wave * 16 + lr][32 + lkb * 8]);
#pragma unroll
        for (int dj = 0; dj < 4; ++dj) {
            short8 vb0 = *reinterpret_cast<const short8*>(&VsT[dj * 16 + lr][lkb * 8]);
            short8 vb1 = *reinterpret_cast<const short8*>(&VsT[dj * 16 + lr][32 + lkb * 8]);
            o[dj] = mfma16(pa0, vb0, o[dj]);
            o[dj] = mfma16(pa1, vb1, o[dj]);
        }
    }

    // epilogue: normalize and store bf16
#pragma unroll
    for (int dj = 0; dj < 4; ++dj) {
#pragma unroll
        for (int q = 0; q < 4; ++q) {
            int row = q0 + wave * 16 + lkb * 4 + q;
            int col = dj * 16 + lr;
            float val = o[dj][q] / lrun[q];
            O[baseo + (size_t)row * ldo + col] = __float2bfloat16(val);
        }
    }
}

// ---------------- moving average (k=25, zero-pad, /25) + LayerNorm ----------------
__global__ __launch_bounds__(256) void mavg_ln_kernel(const float* __restrict__ r,
                                                      const float* __restrict__ g,
                                                      const float* __restrict__ be,
                                                      float* __restrict__ out,
                                                      bf16* __restrict__ outb) {
    const int row = blockIdx.x;
    const int b = row >> 11, l = row & 2047;
    const int t = threadIdx.x, c = t * 4;
    const float* base = r + (size_t)b * LSEQ * DMODEL;
    int j0 = l - 12; if (j0 < 0) j0 = 0;
    int j1 = l + 12; if (j1 > LSEQ - 1) j1 = LSEQ - 1;
    float s0 = 0.f, s1 = 0.f, s2 = 0.f, s3 = 0.f;
    for (int j = j0; j <= j1; ++j) {
        float4 v = *reinterpret_cast<const float4*>(&base[(size_t)j * DMODEL + c]);
        s0 += v.x; s1 += v.y; s2 += v.z; s3 += v.w;
    }
    const float kinv = 1.0f / 25.0f;
    float t0 = s0 * kinv, t1 = s1 * kinv, t2 = s2 * kinv, t3 = s3 * kinv;
    float p1 = t0 + t1 + t2 + t3;
    float p2 = t0 * t0 + t1 * t1 + t2 * t2 + t3 * t3;
    const int lane = t & 63, wv = t >> 6;
#pragma unroll
    for (int off = 1; off < 64; off <<= 1) {
        p1 += __shfl_xor(p1, off);
        p2 += __shfl_xor(p2, off);
    }
    __shared__ float red[8];
    if (lane == 0) { red[wv] = p1; red[4 + wv] = p2; }
    __syncthreads();
    p1 = red[0] + red[1] + red[2] + red[3];
    p2 = red[4] + red[5] + red[6] + red[7];
    const float mu  = p1 * (1.0f / 1024.0f);
    const float var = p2 * (1.0f / 1024.0f) - mu * mu;
    const float inv = rsqrtf(var + 1e-5f);
    float4 gg = *reinterpret_cast<const float4*>(&g[c]);
    float4 bb = *reinterpret_cast<const float4*>(&be[c]);
    float o0 = (t0 - mu) * inv * gg.x + bb.x;
    float o1 = (t1 - mu) * inv * gg.y + bb.y;
    float o2 = (t2 - mu) * inv * gg.z + bb.z;
    float o3 = (t3 - mu) * inv * gg.w + bb.w;
    float4 ov; ov.x = o0; ov.y = o1; ov.z = o2; ov.w = o3;
    *reinterpret_cast<float4*>(&out[(size_t)row * DMODEL + c]) = ov;
    if (outb) {
        union { ushort4 u; bf16 hh[4]; } ob;
        ob.hh[0] = __float2bfloat16(o0);
        ob.hh[1] = __float2bfloat16(o1);
        ob.hh[2] = __float2bfloat16(o2);
        ob.hh[3] = __float2bfloat16(o3);
        reinterpret_cast<ushort4*>(outb + (size_t)row * DMODEL)[t] = ob.u;
    }
}

extern "C" void kernel_launch(void* const* d_in, const int* in_sizes, int n_in,
                              void* d_out, int out_size, void* d_ws, size_t ws_size,
                              hipStream_t stream) {
    const float* x   = (const float*)d_in[0];
    const float* Wq  = (const float*)d_in[1];
    const float* bq  = (const float*)d_in[2];
    const float* Wk  = (const float*)d_in[3];
    const float* bk  = (const float*)d_in[4];
    const float* Wv  = (const float*)d_in[5];
    const float* bv  = (const float*)d_in[6];
    const float* Wo  = (const float*)d_in[7];
    const float* bo  = (const float*)d_in[8];
    const float* W1  = (const float*)d_in[9];
    const float* b1  = (const float*)d_in[10];
    const float* W2  = (const float*)d_in[11];
    const float* b2  = (const float*)d_in[12];
    const float* g1  = (const float*)d_in[13];
    const float* be1 = (const float*)d_in[14];
    const float* g2  = (const float*)d_in[15];
    const float* be2 = (const float*)d_in[16];
    float* out = (float*)d_out;
    char* ws = (char*)d_ws;
    const size_t MB = 1u << 20;

    bf16* xb    = (bf16*)(ws + 0);        //  8MB
    bf16* qkvb  = (bf16*)(ws + 8  * MB);  // 24MB [4096][3072]
    bf16* aob   = (bf16*)(ws + 32 * MB);  //  8MB
    bf16* Wqkvb = (bf16*)(ws + 40 * MB);  //  6MB (Wq|Wk|Wv rows)
    bf16* Wob   = (bf16*)(ws + 46 * MB);  //  2MB
    bf16* W1b   = (bf16*)(ws + 48 * MB);  //  8MB
    bf16* W2b   = (bf16*)(ws + 56 * MB);  //  8MB
    float* y    = (float*)(ws + 64 * MB); // 16MB
    float* rr   = (float*)(ws + 80 * MB); // 16MB (also hosts bqkv early: dead by then)
    float* a    = (float*)(ws + 96 * MB); // 16MB
    bf16* ab    = (bf16*)(ws + 112 * MB); //  8MB
    bf16* hb    = (bf16*)(ws + 120 * MB); // 32MB -> ends at 152MB
    float* bqkv = rr;                     // 12KB, consumed before rr is written

    // dtype conversions
    f2b_kernel<<<(MROWS * DMODEL / 4) / 256, 256, 0, stream>>>(x, xb, MROWS * DMODEL / 4);
    f2b_kernel<<<(DMODEL * DMODEL / 4) / 256, 256, 0, stream>>>(Wq, Wqkvb, DMODEL * DMODEL / 4);
    f2b_kernel<<<(DMODEL * DMODEL / 4) / 256, 256, 0, stream>>>(Wk, Wqkvb + DMODEL * DMODEL, DMODEL * DMODEL / 4);
    f2b_kernel<<<(DMODEL * DMODEL / 4) / 256, 256, 0, stream>>>(Wv, Wqkvb + 2 * DMODEL * DMODEL, DMODEL * DMODEL / 4);
    f2b_kernel<<<(DMODEL * DMODEL / 4) / 256, 256, 0, stream>>>(Wo, Wob, DMODEL * DMODEL / 4);
    f2b_kernel<<<(DFF * DMODEL / 4) / 256, 256, 0, stream>>>(W1, W1b, DFF * DMODEL / 4);
    f2b_kernel<<<(DFF * DMODEL / 4) / 256, 256, 0, stream>>>(W2, W2b, DFF * DMODEL / 4);
    concat3_kernel<<<4, 256, 0, stream>>>(bq, bk, bv, bqkv);

    dim3 blk(256);
    // fused QKV projection -> qkvb [4096][3072]
    gemm_bt<2><<<dim3(32, 24), blk, 0, stream>>>(xb, Wqkvb, bqkv, qkvb, MROWS, 3 * DMODEL, DMODEL);
    // attention (banded)
    attn_kernel<<<dim3(32, 32), blk, 0, stream>>>(qkvb, qkvb + DMODEL, qkvb + 2 * DMODEL,
                                                  aob, 3 * DMODEL, DMODEL);
    // output projection (fp32 out)
    gemm_bt<0><<<dim3(32, 8), blk, 0, stream>>>(aob, Wob, bo, y, MROWS, DMODEL, DMODEL);
    // residual + movavg + LN1
    add_kernel<<<(MROWS * DMODEL / 4) / 256, 256, 0, stream>>>(x, y, rr, MROWS * DMODEL / 4);
    mavg_ln_kernel<<<MROWS, blk, 0, stream>>>(rr, g1, be1, a, ab);
    // FFN
    gemm_bt<1><<<dim3(32, 32), blk, 0, stream>>>(ab, W1b, b1, hb, MROWS, DFF, DMODEL);
    gemm_bt<0><<<dim3(32, 8), blk, 0, stream>>>(hb, W2b, b2, y, MROWS, DMODEL, DFF);
    // residual + movavg + LN2 -> out
    add_kernel<<<(MROWS * DMODEL / 4) / 256, 256, 0, stream>>>(a, y, rr, MROWS * DMODEL / 4);
    mavg_ln_kernel<<<MROWS, blk, 0, stream>>>(rr, g2, be2, out, nullptr);
}

// Round 3
// 396.939 us; speedup vs baseline: 1.5109x; 1.0862x over previous
//
#include <hip/hip_runtime.h>
#include <hip/hip_bf16.h>
#include <math.h>

#define DMODEL 1024
#define LSEQ   2048
#define BATCH  2
#define NHEADS 16
#define DHEAD  64
#define DFF    4096
#define MROWS  (BATCH*LSEQ)   // 4096

typedef __attribute__((ext_vector_type(8))) short short8;
typedef __attribute__((ext_vector_type(4))) float f32x4;
using bf16 = __hip_bfloat16;

static __device__ __forceinline__ f32x4 mfma16(short8 a, short8 b, f32x4 c) {
    return __builtin_amdgcn_mfma_f32_16x16x32_bf16(a, b, c, 0, 0, 0);
}

static __device__ __forceinline__ void gload16(const void* g, void* l) {
    __builtin_amdgcn_global_load_lds(
        (const __attribute__((address_space(1))) char*)g,
        (__attribute__((address_space(3))) char*)l, 16, 0, 0);
}

// ---------------- fp32 -> bf16 conversion ----------------
__global__ void f2b_kernel(const float* __restrict__ in, bf16* __restrict__ out, int n4) {
    int i = blockIdx.x * blockDim.x + threadIdx.x;
    if (i >= n4) return;
    float4 v = reinterpret_cast<const float4*>(in)[i];
    union { ushort4 u; bf16 h[4]; } o;
    o.h[0] = __float2bfloat16(v.x);
    o.h[1] = __float2bfloat16(v.y);
    o.h[2] = __float2bfloat16(v.z);
    o.h[3] = __float2bfloat16(v.w);
    reinterpret_cast<ushort4*>(out)[i] = o.u;
}

// ---------------- bias concat (bq,bk,bv -> 3072) ----------------
__global__ void concat3_kernel(const float* __restrict__ a, const float* __restrict__ b,
                               const float* __restrict__ c, float* __restrict__ o) {
    int i = blockIdx.x * blockDim.x + threadIdx.x;
    if (i < DMODEL) { o[i] = a[i]; o[DMODEL + i] = b[i]; o[2 * DMODEL + i] = c[i]; }
}

// ---------------- split-K reduce: out = res + sum_s P_s + bias ----------------
template<int S>
__global__ __launch_bounds__(256) void reduce_kernel(const float* __restrict__ res,
                                                     const float* __restrict__ P,
                                                     const float* __restrict__ bias,
                                                     float* __restrict__ out, int n4) {
    int i = blockIdx.x * blockDim.x + threadIdx.x;
    if (i >= n4) return;
    float4 acc = reinterpret_cast<const float4*>(res)[i];
#pragma unroll
    for (int s = 0; s < S; ++s) {
        float4 p = reinterpret_cast<const float4*>(P)[i + (size_t)s * (MROWS * DMODEL / 4)];
        acc.x += p.x; acc.y += p.y; acc.z += p.z; acc.w += p.w;
    }
    float4 bs = reinterpret_cast<const float4*>(bias)[i & (DMODEL / 4 - 1)];
    acc.x += bs.x; acc.y += bs.y; acc.z += bs.z; acc.w += bs.w;
    reinterpret_cast<float4*>(out)[i] = acc;
}

// ---------------- GEMM (m97 structure): C[M,N] = A[M,Ksl]@W[N,Ksl]^T (+bias) ----------
// linear LDS + global_load_lds width=16; 128x128 tile, BK=32, 4 waves, 4x4 frags/wave
// EPI: 0 = fp32+bias, 1 = GELU+bf16, 2 = bf16+bias, 3 = fp32 partial (no bias),
//      blockIdx.z = K-split index (A/W advanced by z*K, C -> Cout + z*M*N)
template<int EPI>
__global__ __launch_bounds__(256) void gemm_bt(const bf16* __restrict__ A,
                                               const bf16* __restrict__ W,
                                               const float* __restrict__ bias,
                                               void* __restrict__ Cout,
                                               int M, int N, int lda, int ldw, int K) {
    __shared__ bf16 As[128 * 32];
    __shared__ bf16 Ws[128 * 32];
    const int t    = threadIdx.x;
    const int m0   = blockIdx.x * 128;
    const int n0   = blockIdx.y * 128;
    const int sk   = blockIdx.z;
    const int wave = t >> 6, lane = t & 63;
    const int wr   = (wave >> 1) * 64;
    const int wc   = (wave & 1) * 64;
    const int lr   = lane & 15, lkb = lane >> 4;
    const int srow = t >> 2, scol = (t & 3) * 8;

    const bf16* Ag0 = A + (size_t)(m0 + srow) * lda + (size_t)sk * K + scol;
    const bf16* Ag1 = A + (size_t)(m0 + 64 + srow) * lda + (size_t)sk * K + scol;
    const bf16* Wg0 = W + (size_t)(n0 + srow) * ldw + (size_t)sk * K + scol;
    const bf16* Wg1 = W + (size_t)(n0 + 64 + srow) * ldw + (size_t)sk * K + scol;
    bf16* AsW = As + wave * 512;   // wave-uniform LDS base; HW adds lane*16B
    bf16* WsW = Ws + wave * 512;

    f32x4 acc[4][4];
#pragma unroll
    for (int i = 0; i < 4; ++i)
#pragma unroll
        for (int j = 0; j < 4; ++j)
            acc[i][j] = (f32x4){0.f, 0.f, 0.f, 0.f};

    for (int k0 = 0; k0 < K; k0 += 32) {
        gload16(Ag0 + k0, AsW);
        gload16(Ag1 + k0, AsW + 2048);
        gload16(Wg0 + k0, WsW);
        gload16(Wg1 + k0, WsW + 2048);
        __syncthreads();
        short8 a[4], b[4];
#pragma unroll
        for (int i = 0; i < 4; ++i)
            a[i] = *reinterpret_cast<const short8*>(&As[(wr + i * 16 + lr) * 32 + lkb * 8]);
#pragma unroll
        for (int j = 0; j < 4; ++j)
            b[j] = *reinterpret_cast<const short8*>(&Ws[(wc + j * 16 + lr) * 32 + lkb * 8]);
#pragma unroll
        for (int i = 0; i < 4; ++i)
#pragma unroll
            for (int j = 0; j < 4; ++j)
                acc[i][j] = mfma16(a[i], b[j], acc[i][j]);
        __syncthreads();
    }

    // epilogue: C/D layout col=lane&15, row=(lane>>4)*4+reg
    float* Cp = (float*)Cout + (EPI == 3 ? (size_t)sk * M * N : 0);
#pragma unroll
    for (int i = 0; i < 4; ++i) {
#pragma unroll
        for (int j = 0; j < 4; ++j) {
            int col = n0 + wc + j * 16 + lr;
            float bsv = (EPI == 3) ? 0.f : bias[col];
#pragma unroll
            for (int q = 0; q < 4; ++q) {
                int row = m0 + wr + i * 16 + lkb * 4 + q;
                float v = acc[i][j][q] + bsv;
                if (EPI == 0 || EPI == 3) {
                    Cp[(size_t)row * N + col] = v;
                } else if (EPI == 1) {
                    float gv = 0.5f * v * (1.0f + erff(v * 0.70710678118654752f));
                    reinterpret_cast<bf16*>(Cout)[(size_t)row * N + col] = __float2bfloat16(gv);
                } else {
                    reinterpret_cast<bf16*>(Cout)[(size_t)row * N + col] = __float2bfloat16(v);
                }
            }
        }
    }
}

// ---------------- fused attention (flash-style, bf16 MFMA, banded) ----------------
// time bias -0.1|i-j|: keys with |i-j|>=193 contribute <~1e-7 relative -> band
// [qt-3, qt+3] (7 of 32 K-tiles).
// grid: (L/64 q-tiles, B*H); block 256 threads (4 waves, 16 q-rows each)
__global__ __launch_bounds__(256) void attn_kernel(const bf16* __restrict__ Q,
                                                   const bf16* __restrict__ Km,
                                                   const bf16* __restrict__ V,
                                                   bf16* __restrict__ O,
                                                   int ldq, int ldo) {
    __shared__ bf16 Qs[64][72];
    __shared__ bf16 Ks[64][72];
    __shared__ bf16 VsT[64][72];   // transposed V tile: VsT[d][m]
    __shared__ bf16 Ps[64][72];
    const int t    = threadIdx.x;
    const int wave = t >> 6, lane = t & 63;
    const int lr   = lane & 15, lkb = lane >> 4;
    const int qt   = blockIdx.x;
    const int q0   = qt * 64;
    const int b    = blockIdx.y >> 4, h = blockIdx.y & 15;
    const size_t base  = (size_t)b * LSEQ * ldq + (size_t)h * DHEAD;
    const size_t baseo = (size_t)b * LSEQ * ldo + (size_t)h * DHEAD;

#pragma unroll
    for (int p = 0; p < 2; ++p) {
        int idx = t + p * 256;
        int row = idx >> 3, c = (idx & 7) * 8;
        *reinterpret_cast<uint4*>(&Qs[row][c]) =
            *reinterpret_cast<const uint4*>(&Q[base + (size_t)(q0 + row) * ldq + c]);
    }
    __syncthreads();
    short8 qa[2];
    qa[0] = *reinterpret_cast<const short8*>(&Qs[wave * 16 + lr][lkb * 8]);
    qa[1] = *reinterpret_cast<const short8*>(&Qs[wave * 16 + lr][32 + lkb * 8]);

    f32x4 o[4];
#pragma unroll
    for (int dj = 0; dj < 4; ++dj) o[dj] = (f32x4){0.f, 0.f, 0.f, 0.f};
    float mrun[4], lrun[4];
#pragma unroll
    for (int q = 0; q < 4; ++q) { mrun[q] = -1e30f; lrun[q] = 0.f; }

    int kt0 = qt - 3; if (kt0 < 0) kt0 = 0;
    int kt1 = qt + 3; if (kt1 > LSEQ / 64 - 1) kt1 = LSEQ / 64 - 1;

    for (int kt = kt0; kt <= kt1; ++kt) {
        const int k0 = kt * 64;
        __syncthreads();   // protect Ks/VsT reads of previous iteration
#pragma unroll
        for (int p = 0; p < 2; ++p) {
            int idx = t + p * 256;
            int row = idx >> 3, c = (idx & 7) * 8;
            *reinterpret_cast<uint4*>(&Ks[row][c]) =
                *reinterpret_cast<const uint4*>(&Km[base + (size_t)(k0 + row) * ldq + c]);
        }
        {
            const int vl = lane, vw = wave;
#pragma unroll
            for (int p = 0; p < 2; ++p) {
                int c = vw * 8 + p * 32;
                union { uint4 u; bf16 hh[8]; } tv;
                tv.u = *reinterpret_cast<const uint4*>(&V[base + (size_t)(k0 + vl) * ldq + c]);
#pragma unroll
                for (int e = 0; e < 8; ++e) VsT[c + e][vl] = tv.hh[e];
            }
        }
        __syncthreads();

        f32x4 s[4];
#pragma unroll
        for (int j = 0; j < 4; ++j) {
            short8 kb0 = *reinterpret_cast<const short8*>(&Ks[j * 16 + lr][lkb * 8]);
            short8 kb1 = *reinterpret_cast<const short8*>(&Ks[j * 16 + lr][32 + lkb * 8]);
            f32x4 z = (f32x4){0.f, 0.f, 0.f, 0.f};
            z = mfma16(qa[0], kb0, z);
            z = mfma16(qa[1], kb1, z);
            s[j] = z;
        }
        float mx[4];
#pragma unroll
        for (int q = 0; q < 4; ++q) mx[q] = -1e30f;
#pragma unroll
        for (int j = 0; j < 4; ++j) {
            int cm = k0 + j * 16 + lr;
#pragma unroll
            for (int q = 0; q < 4; ++q) {
                int rq = q0 + wave * 16 + lkb * 4 + q;
                float sv = s[j][q] * 0.125f - 0.1f * fabsf((float)(rq - cm));
                s[j][q] = sv;
                mx[q] = fmaxf(mx[q], sv);
            }
        }
#pragma unroll
        for (int q = 0; q < 4; ++q) {
#pragma unroll
            for (int off = 1; off < 16; off <<= 1)
                mx[q] = fmaxf(mx[q], __shfl_xor(mx[q], off));
        }
        float alpha[4];
#pragma unroll
        for (int q = 0; q < 4; ++q) {
            float mnew = fmaxf(mrun[q], mx[q]);
            alpha[q] = __expf(mrun[q] - mnew);
            mrun[q] = mnew;
        }
        float rs[4] = {0.f, 0.f, 0.f, 0.f};
#pragma unroll
        for (int j = 0; j < 4; ++j) {
#pragma unroll
            for (int q = 0; q < 4; ++q) {
                float p = __expf(s[j][q] - mrun[q]);
                rs[q] += p;
                Ps[wave * 16 + lkb * 4 + q][j * 16 + lr] = __float2bfloat16(p);
            }
        }
#pragma unroll
        for (int q = 0; q < 4; ++q) {
#pragma unroll
            for (int off = 1; off < 16; off <<= 1)
                rs[q] += __shfl_xor(rs[q], off);
            lrun[q] = lrun[q] * alpha[q] + rs[q];
        }
#pragma unroll
        for (int dj = 0; dj < 4; ++dj)
#pragma unroll
            for (int q = 0; q < 4; ++q) o[dj][q] *= alpha[q];
        // no barrier: Ps rows are wave-private (same wave writes and reads)

        short8 pa0 = *reinterpret_cast<const short8*>(&Ps[wave * 16 + lr][lkb * 8]);
        short8 pa1 = *reinterpret_cast<const short8*>(&Ps[wave * 16 + lr][32 + lkb * 8]);
#pragma unroll
        for (int dj = 0; dj < 4; ++dj) {
            short8 vb0 = *reinterpret_cast<const short8*>(&VsT[dj * 16 + lr][lkb * 8]);
            short8 vb1 = *reinterpret_cast<const short8*>(&VsT[dj * 16 + lr][32 + lkb * 8]);
            o[dj] = mfma16(pa0, vb0, o[dj]);
            o[dj] = mfma16(pa1, vb1, o[dj]);
        }
    }

#pragma unroll
    for (int dj = 0; dj < 4; ++dj) {
#pragma unroll
        for (int q = 0; q < 4; ++q) {
            int row = q0 + wave * 16 + lkb * 4 + q;
            int col = dj * 16 + lr;
            float val = o[dj][q] / lrun[q];
            O[baseo + (size_t)row * ldo + col] = __float2bfloat16(val);
        }
    }
}

// ---------------- moving average (k=25, zero-pad, /25) + LayerNorm ----------------
__global__ __launch_bounds__(256) void mavg_ln_kernel(const float* __restrict__ r,
                                                      const float* __restrict__ g,
                                                      const float* __restrict__ be,
                                                      float* __restrict__ out,
                                                      bf16* __restrict__ outb) {
    const int row = blockIdx.x;
    const int b = row >> 11, l = row & 2047;
    const int t = threadIdx.x, c = t * 4;
    const float* base = r + (size_t)b * LSEQ * DMODEL;
    int j0 = l - 12; if (j0 < 0) j0 = 0;
    int j1 = l + 12; if (j1 > LSEQ - 1) j1 = LSEQ - 1;
    float s0 = 0.f, s1 = 0.f, s2 = 0.f, s3 = 0.f;
    for (int j = j0; j <= j1; ++j) {
        float4 v = *reinterpret_cast<const float4*>(&base[(size_t)j * DMODEL + c]);
        s0 += v.x; s1 += v.y; s2 += v.z; s3 += v.w;
    }
    const float kinv = 1.0f / 25.0f;
    float t0 = s0 * kinv, t1 = s1 * kinv, t2 = s2 * kinv, t3 = s3 * kinv;
    float p1 = t0 + t1 + t2 + t3;
    float p2 = t0 * t0 + t1 * t1 + t2 * t2 + t3 * t3;
    const int lane = t & 63, wv = t >> 6;
#pragma unroll
    for (int off = 1; off < 64; off <<= 1) {
        p1 += __shfl_xor(p1, off);
        p2 += __shfl_xor(p2, off);
    }
    __shared__ float red[8];
    if (lane == 0) { red[wv] = p1; red[4 + wv] = p2; }
    __syncthreads();
    p1 = red[0] + red[1] + red[2] + red[3];
    p2 = red[4] + red[5] + red[6] + red[7];
    const float mu  = p1 * (1.0f / 1024.0f);
    const float var = p2 * (1.0f / 1024.0f) - mu * mu;
    const float inv = rsqrtf(var + 1e-5f);
    float4 gg = *reinterpret_cast<const float4*>(&g[c]);
    float4 bb = *reinterpret_cast<const float4*>(&be[c]);
    float o0 = (t0 - mu) * inv * gg.x + bb.x;
    float o1 = (t1 - mu) * inv * gg.y + bb.y;
    float o2 = (t2 - mu) * inv * gg.z + bb.z;
    float o3 = (t3 - mu) * inv * gg.w + bb.w;
    float4 ov; ov.x = o0; ov.y = o1; ov.z = o2; ov.w = o3;
    *reinterpret_cast<float4*>(&out[(size_t)row * DMODEL + c]) = ov;
    if (outb) {
        union { ushort4 u; bf16 hh[4]; } ob;
        ob.hh[0] = __float2bfloat16(o0);
        ob.hh[1] = __float2bfloat16(o1);
        ob.hh[2] = __float2bfloat16(o2);
        ob.hh[3] = __float2bfloat16(o3);
        reinterpret_cast<ushort4*>(outb + (size_t)row * DMODEL)[t] = ob.u;
    }
}

extern "C" void kernel_launch(void* const* d_in, const int* in_sizes, int n_in,
                              void* d_out, int out_size, void* d_ws, size_t ws_size,
                              hipStream_t stream) {
    const float* x   = (const float*)d_in[0];
    const float* Wq  = (const float*)d_in[1];
    const float* bq  = (const float*)d_in[2];
    const float* Wk  = (const float*)d_in[3];
    const float* bk  = (const float*)d_in[4];
    const float* Wv  = (const float*)d_in[5];
    const float* bv  = (const float*)d_in[6];
    const float* Wo  = (const float*)d_in[7];
    const float* bo  = (const float*)d_in[8];
    const float* W1  = (const float*)d_in[9];
    const float* b1  = (const float*)d_in[10];
    const float* W2  = (const float*)d_in[11];
    const float* b2  = (const float*)d_in[12];
    const float* g1  = (const float*)d_in[13];
    const float* be1 = (const float*)d_in[14];
    const float* g2  = (const float*)d_in[15];
    const float* be2 = (const float*)d_in[16];
    float* out = (float*)d_out;
    char* ws = (char*)d_ws;
    const size_t MB = 1u << 20;

    // timeline-overlapped layout (152MB total):
    float* rr   = (float*)(ws + 0);        // 16MB  (steps 5-6, 9-10)
    bf16* xb    = (bf16*)(ws + 0);         //  8MB  (steps 1-2; dead before rr)
    bf16* qkvb  = (bf16*)(ws + 16 * MB);   // 24MB  (2-3)
    bf16* ab    = (bf16*)(ws + 16 * MB);   //  8MB  (6-7; qkvb dead)
    bf16* hb    = (bf16*)(ws + 24 * MB);   // 32MB  (7-8; over qkvb tail/aob/Wqkvb/Wob)
    bf16* aob   = (bf16*)(ws + 40 * MB);   //  8MB  (3-4)
    bf16* Wqkvb = (bf16*)(ws + 48 * MB);   //  6MB  (1-2)
    bf16* Wob   = (bf16*)(ws + 54 * MB);   //  2MB  (1-4)
    bf16* W1b   = (bf16*)(ws + 56 * MB);   //  8MB  (1-7)
    bf16* W2b   = (bf16*)(ws + 64 * MB);   //  8MB  (1-8)
    float* P    = (float*)(ws + 72 * MB);  // 64MB  partials (4-5: 2 used; 8-9: 4 used)
    float* a    = (float*)(ws + 136 * MB); // 16MB  (6-9)
    float* bqkv = (float*)(ws + 136 * MB); // 12KB  (1-2; dead before a)

    // 1. dtype conversions
    f2b_kernel<<<(MROWS * DMODEL / 4) / 256, 256, 0, stream>>>(x, xb, MROWS * DMODEL / 4);
    f2b_kernel<<<(DMODEL * DMODEL / 4) / 256, 256, 0, stream>>>(Wq, Wqkvb, DMODEL * DMODEL / 4);
    f2b_kernel<<<(DMODEL * DMODEL / 4) / 256, 256, 0, stream>>>(Wk, Wqkvb + DMODEL * DMODEL, DMODEL * DMODEL / 4);
    f2b_kernel<<<(DMODEL * DMODEL / 4) / 256, 256, 0, stream>>>(Wv, Wqkvb + 2 * DMODEL * DMODEL, DMODEL * DMODEL / 4);
    f2b_kernel<<<(DMODEL * DMODEL / 4) / 256, 256, 0, stream>>>(Wo, Wob, DMODEL * DMODEL / 4);
    f2b_kernel<<<(DFF * DMODEL / 4) / 256, 256, 0, stream>>>(W1, W1b, DFF * DMODEL / 4);
    f2b_kernel<<<(DFF * DMODEL / 4) / 256, 256, 0, stream>>>(W2, W2b, DFF * DMODEL / 4);
    concat3_kernel<<<4, 256, 0, stream>>>(bq, bk, bv, bqkv);

    dim3 blk(256);
    // 2. fused QKV projection -> qkvb [4096][3072]
    gemm_bt<2><<<dim3(32, 24), blk, 0, stream>>>(xb, Wqkvb, bqkv, qkvb,
                                                 MROWS, 3 * DMODEL, DMODEL, DMODEL, DMODEL);
    // 3. attention (banded +-3 tiles)
    attn_kernel<<<dim3(32, 32), blk, 0, stream>>>(qkvb, qkvb + DMODEL, qkvb + 2 * DMODEL,
                                                  aob, 3 * DMODEL, DMODEL);
    // 4. output projection, split-K=2 -> P[0:2]
    gemm_bt<3><<<dim3(32, 8, 2), blk, 0, stream>>>(aob, Wob, nullptr, P,
                                                   MROWS, DMODEL, DMODEL, DMODEL, DMODEL / 2);
    // 5. rr = x + P0 + P1 + bo
    reduce_kernel<2><<<(MROWS * DMODEL / 4) / 256, blk, 0, stream>>>(x, P, bo, rr, MROWS * DMODEL / 4);
    // 6. movavg + LN1
    mavg_ln_kernel<<<MROWS, blk, 0, stream>>>(rr, g1, be1, a, ab);
    // 7. FF1 (GELU, bf16 out)
    gemm_bt<1><<<dim3(32, 32), blk, 0, stream>>>(ab, W1b, b1, hb,
                                                 MROWS, DFF, DMODEL, DMODEL, DMODEL);
    // 8. FF2, split-K=4 -> P[0:4]
    gemm_bt<3><<<dim3(32, 8, 4), blk, 0, stream>>>(hb, W2b, nullptr, P,
                                                   MROWS, DMODEL, DFF, DFF, DFF / 4);
    // 9. rr = a + sum(P) + b2
    reduce_kernel<4><<<(MROWS * DMODEL / 4) / 256, blk, 0, stream>>>(a, P, b2, rr, MROWS * DMODEL / 4);
    // 10. movavg + LN2 -> out
    mavg_ln_kernel<<<MROWS, blk, 0, stream>>>(rr, g2, be2, out, nullptr);
}

// Round 4
// 362.608 us; speedup vs baseline: 1.6539x; 1.0947x over previous
//
#include <hip/hip_runtime.h>
#include <hip/hip_bf16.h>
#include <math.h>

#define DMODEL 1024
#define LSEQ   2048
#define BATCH  2
#define NHEADS 16
#define DHEAD  64
#define DFF    4096
#define MROWS  (BATCH*LSEQ)   // 4096

typedef __attribute__((ext_vector_type(8))) short short8;
typedef __attribute__((ext_vector_type(4))) float f32x4;
using bf16 = __hip_bfloat16;

static __device__ __forceinline__ f32x4 mfma16(short8 a, short8 b, f32x4 c) {
    return __builtin_amdgcn_mfma_f32_16x16x32_bf16(a, b, c, 0, 0, 0);
}

static __device__ __forceinline__ void gload16(const void* g, void* l) {
    __builtin_amdgcn_global_load_lds(
        (const __attribute__((address_space(1))) char*)g,
        (__attribute__((address_space(3))) char*)l, 16, 0, 0);
}

static __device__ __forceinline__ bf16 b16(float v) { return __float2bfloat16(v); }

// ---------------- fp32 -> bf16 conversion (multi-buffer via blockIdx.y) ----------------
__global__ void f2b1_kernel(const float* __restrict__ in, bf16* __restrict__ out, int n4) {
    int i = blockIdx.x * blockDim.x + threadIdx.x;
    if (i >= n4) return;
    float4 v = reinterpret_cast<const float4*>(in)[i];
    union { ushort4 u; bf16 h[4]; } o;
    o.h[0] = b16(v.x); o.h[1] = b16(v.y); o.h[2] = b16(v.z); o.h[3] = b16(v.w);
    reinterpret_cast<ushort4*>(out)[i] = o.u;
}

__global__ void f2b4_kernel(const float* p0, const float* p1, const float* p2, const float* p3,
                            bf16* o0, bf16* o1, bf16* o2, bf16* o3, int n4) {
    const float* in; bf16* out;
    switch (blockIdx.y) {
        case 0: in = p0; out = o0; break;
        case 1: in = p1; out = o1; break;
        case 2: in = p2; out = o2; break;
        default: in = p3; out = o3; break;
    }
    int i = blockIdx.x * blockDim.x + threadIdx.x;
    if (i >= n4) return;
    float4 v = reinterpret_cast<const float4*>(in)[i];
    union { ushort4 u; bf16 h[4]; } o;
    o.h[0] = b16(v.x); o.h[1] = b16(v.y); o.h[2] = b16(v.z); o.h[3] = b16(v.w);
    reinterpret_cast<ushort4*>(out)[i] = o.u;
}

// ---------------- bias concat (bq,bk,bv -> 3072) ----------------
__global__ void concat3_kernel(const float* __restrict__ a, const float* __restrict__ b,
                               const float* __restrict__ c, float* __restrict__ o) {
    int i = blockIdx.x * blockDim.x + threadIdx.x;
    if (i < DMODEL) { o[i] = a[i]; o[DMODEL + i] = b[i]; o[2 * DMODEL + i] = c[i]; }
}

// ---------------- split-K reduce: out = res + sum_s P_s + bias ----------------
template<int S>
__global__ __launch_bounds__(256) void reduce_kernel(const float* __restrict__ res,
                                                     const float* __restrict__ P,
                                                     const float* __restrict__ bias,
                                                     float* __restrict__ out, int n4) {
    int i = blockIdx.x * blockDim.x + threadIdx.x;
    if (i >= n4) return;
    float4 acc = reinterpret_cast<const float4*>(res)[i];
#pragma unroll
    for (int s = 0; s < S; ++s) {
        float4 p = reinterpret_cast<const float4*>(P)[i + (size_t)s * (MROWS * DMODEL / 4)];
        acc.x += p.x; acc.y += p.y; acc.z += p.z; acc.w += p.w;
    }
    float4 bs = reinterpret_cast<const float4*>(bias)[i & (DMODEL / 4 - 1)];
    acc.x += bs.x; acc.y += bs.y; acc.z += bs.z; acc.w += bs.w;
    reinterpret_cast<float4*>(out)[i] = acc;
}

// ---------------- GEMM: C[M,N] = A[M,Ksl]@W[N,Ksl]^T (+bias) ----------------
// 2-phase double-buffered pipeline (T3 minimum recipe): issue next-tile
// global_load_lds BEFORE current tile's ds_read+MFMA; one barrier per K-step.
// Operand-swapped MFMA (mfma(b,a)) so each lane holds 4 consecutive N-cols:
// vectorized epilogue stores (8B bf16 / 16B f32).
// EPI: 0 = fp32+bias, 1 = GELU(tanh approx)+bf16, 2 = bf16+bias,
//      3 = fp32 partial (no bias), blockIdx.z = K-split index
template<int EPI>
__global__ __launch_bounds__(256) void gemm_bt(const bf16* __restrict__ A,
                                               const bf16* __restrict__ W,
                                               const float* __restrict__ bias,
                                               void* __restrict__ Cout,
                                               int M, int N, int lda, int ldw, int K) {
    __shared__ bf16 sm[16384];   // [2 bufs][A 4096 | W 4096] = 32 KB
    const int t    = threadIdx.x;
    const int m0   = blockIdx.x * 128;
    const int n0   = blockIdx.y * 128;
    const int sk   = blockIdx.z;
    const int wave = t >> 6, lane = t & 63;
    const int wr   = (wave >> 1) * 64;
    const int wc   = (wave & 1) * 64;
    const int lr   = lane & 15, lkb = lane >> 4;
    const int srow = t >> 2, scol = (t & 3) * 8;

    const bf16* Ag0 = A + (size_t)(m0 + srow) * lda + (size_t)sk * K + scol;
    const bf16* Ag1 = A + (size_t)(m0 + 64 + srow) * lda + (size_t)sk * K + scol;
    const bf16* Wg0 = W + (size_t)(n0 + srow) * ldw + (size_t)sk * K + scol;
    const bf16* Wg1 = W + (size_t)(n0 + 64 + srow) * ldw + (size_t)sk * K + scol;

    f32x4 acc[4][4];
#pragma unroll
    for (int i = 0; i < 4; ++i)
#pragma unroll
        for (int j = 0; j < 4; ++j)
            acc[i][j] = (f32x4){0.f, 0.f, 0.f, 0.f};

    const int nt = K >> 5;
    auto stage = [&](int buf, int kt) {
        const int off = kt * 32;
        bf16* AsW = sm + buf * 4096 + wave * 512;          // wave-uniform base
        bf16* WsW = sm + 8192 + buf * 4096 + wave * 512;   // HW adds lane*16B
        gload16(Ag0 + off, AsW);
        gload16(Ag1 + off, AsW + 2048);
        gload16(Wg0 + off, WsW);
        gload16(Wg1 + off, WsW + 2048);
    };

    stage(0, 0);
    __syncthreads();                 // vmcnt(0) drain of prologue stage
    int cur = 0;
    for (int kt = 0; kt < nt; ++kt) {
        if (kt + 1 < nt) stage(cur ^ 1, kt + 1);   // overlap issue with compute
        short8 a[4], b[4];
#pragma unroll
        for (int i = 0; i < 4; ++i)
            a[i] = *reinterpret_cast<const short8*>(
                &sm[cur * 4096 + (wr + i * 16 + lr) * 32 + lkb * 8]);
#pragma unroll
        for (int j = 0; j < 4; ++j)
            b[j] = *reinterpret_cast<const short8*>(
                &sm[8192 + cur * 4096 + (wc + j * 16 + lr) * 32 + lkb * 8]);
#pragma unroll
        for (int i = 0; i < 4; ++i)
#pragma unroll
            for (int j = 0; j < 4; ++j)
                acc[i][j] = mfma16(b[j], a[i], acc[i][j]);   // swapped operands
        __syncthreads();             // drains next-tile stage (vmcnt) + lgkm
        cur ^= 1;
    }

    // epilogue: swapped layout -> lane holds M-row (m0+wr+i*16+lr),
    // N-cols (n0+wc+j*16+lkb*4 + 0..3) consecutive
    float* Cp = (float*)Cout + (EPI == 3 ? (size_t)sk * M * N : 0);
#pragma unroll
    for (int i = 0; i < 4; ++i) {
        const int row = m0 + wr + i * 16 + lr;
#pragma unroll
        for (int j = 0; j < 4; ++j) {
            const int col = n0 + wc + j * 16 + lkb * 4;
            f32x4 v = acc[i][j];
            if (EPI != 3) {
                float4 bs = *reinterpret_cast<const float4*>(&bias[col]);
                v[0] += bs.x; v[1] += bs.y; v[2] += bs.z; v[3] += bs.w;
            }
            if (EPI == 0 || EPI == 3) {
                float4 ov; ov.x = v[0]; ov.y = v[1]; ov.z = v[2]; ov.w = v[3];
                *reinterpret_cast<float4*>(&Cp[(size_t)row * N + col]) = ov;
            } else if (EPI == 1) {
                union { ushort4 u; bf16 h[4]; } ob;
#pragma unroll
                for (int q = 0; q < 4; ++q) {
                    float x = v[q];
                    float u2 = x * (1.5957691216f + 0.0713548162f * x * x); // 2*0.79788456*(x+0.044715x^3)
                    float e = __expf(fminf(u2, 60.f));
                    ob.h[q] = b16(x * (e / (e + 1.f)));   // x*sigmoid(2u) = 0.5x(1+tanh u)
                }
                *reinterpret_cast<ushort4*>(
                    &reinterpret_cast<bf16*>(Cout)[(size_t)row * N + col]) = ob.u;
            } else {
                union { ushort4 u; bf16 h[4]; } ob;
#pragma unroll
                for (int q = 0; q < 4; ++q) ob.h[q] = b16(v[q]);
                *reinterpret_cast<ushort4*>(
                    &reinterpret_cast<bf16*>(Cout)[(size_t)row * N + col]) = ob.u;
            }
        }
    }
}

// ---------------- fused attention (flash-style, bf16 MFMA, banded) ----------------
// time bias -0.1|i-j|: keys with |i-j|>=193 contribute <~1e-7 relative -> band
// [qt-3, qt+3] (7 of 32 K-tiles).
__global__ __launch_bounds__(256) void attn_kernel(const bf16* __restrict__ Q,
                                                   const bf16* __restrict__ Km,
                                                   const bf16* __restrict__ V,
                                                   bf16* __restrict__ O,
                                                   int ldq, int ldo) {
    __shared__ bf16 Qs[64][72];
    __shared__ bf16 Ks[64][72];
    __shared__ bf16 VsT[64][72];   // transposed V tile: VsT[d][m]
    __shared__ bf16 Ps[64][72];
    const int t    = threadIdx.x;
    const int wave = t >> 6, lane = t & 63;
    const int lr   = lane & 15, lkb = lane >> 4;
    const int qt   = blockIdx.x;
    const int q0   = qt * 64;
    const int b    = blockIdx.y >> 4, h = blockIdx.y & 15;
    const size_t base  = (size_t)b * LSEQ * ldq + (size_t)h * DHEAD;
    const size_t baseo = (size_t)b * LSEQ * ldo + (size_t)h * DHEAD;

#pragma unroll
    for (int p = 0; p < 2; ++p) {
        int idx = t + p * 256;
        int row = idx >> 3, c = (idx & 7) * 8;
        *reinterpret_cast<uint4*>(&Qs[row][c]) =
            *reinterpret_cast<const uint4*>(&Q[base + (size_t)(q0 + row) * ldq + c]);
    }
    __syncthreads();
    short8 qa[2];
    qa[0] = *reinterpret_cast<const short8*>(&Qs[wave * 16 + lr][lkb * 8]);
    qa[1] = *reinterpret_cast<const short8*>(&Qs[wave * 16 + lr][32 + lkb * 8]);

    f32x4 o[4];
#pragma unroll
    for (int dj = 0; dj < 4; ++dj) o[dj] = (f32x4){0.f, 0.f, 0.f, 0.f};
    float mrun[4], lrun[4];
#pragma unroll
    for (int q = 0; q < 4; ++q) { mrun[q] = -1e30f; lrun[q] = 0.f; }

    int kt0 = qt - 3; if (kt0 < 0) kt0 = 0;
    int kt1 = qt + 3; if (kt1 > LSEQ / 64 - 1) kt1 = LSEQ / 64 - 1;

    for (int kt = kt0; kt <= kt1; ++kt) {
        const int k0 = kt * 64;
        __syncthreads();
#pragma unroll
        for (int p = 0; p < 2; ++p) {
            int idx = t + p * 256;
            int row = idx >> 3, c = (idx & 7) * 8;
            *reinterpret_cast<uint4*>(&Ks[row][c]) =
                *reinterpret_cast<const uint4*>(&Km[base + (size_t)(k0 + row) * ldq + c]);
        }
        {
            const int vl = lane, vw = wave;
#pragma unroll
            for (int p = 0; p < 2; ++p) {
                int c = vw * 8 + p * 32;
                union { uint4 u; bf16 hh[8]; } tv;
                tv.u = *reinterpret_cast<const uint4*>(&V[base + (size_t)(k0 + vl) * ldq + c]);
#pragma unroll
                for (int e = 0; e < 8; ++e) VsT[c + e][vl] = tv.hh[e];
            }
        }
        __syncthreads();

        f32x4 s[4];
#pragma unroll
        for (int j = 0; j < 4; ++j) {
            short8 kb0 = *reinterpret_cast<const short8*>(&Ks[j * 16 + lr][lkb * 8]);
            short8 kb1 = *reinterpret_cast<const short8*>(&Ks[j * 16 + lr][32 + lkb * 8]);
            f32x4 z = (f32x4){0.f, 0.f, 0.f, 0.f};
            z = mfma16(qa[0], kb0, z);
            z = mfma16(qa[1], kb1, z);
            s[j] = z;
        }
        float mx[4];
#pragma unroll
        for (int q = 0; q < 4; ++q) mx[q] = -1e30f;
#pragma unroll
        for (int j = 0; j < 4; ++j) {
            int cm = k0 + j * 16 + lr;
#pragma unroll
            for (int q = 0; q < 4; ++q) {
                int rq = q0 + wave * 16 + lkb * 4 + q;
                float sv = s[j][q] * 0.125f - 0.1f * fabsf((float)(rq - cm));
                s[j][q] = sv;
                mx[q] = fmaxf(mx[q], sv);
            }
        }
#pragma unroll
        for (int q = 0; q < 4; ++q) {
#pragma unroll
            for (int off = 1; off < 16; off <<= 1)
                mx[q] = fmaxf(mx[q], __shfl_xor(mx[q], off));
        }
        float alpha[4];
#pragma unroll
        for (int q = 0; q < 4; ++q) {
            float mnew = fmaxf(mrun[q], mx[q]);
            alpha[q] = __expf(mrun[q] - mnew);
            mrun[q] = mnew;
        }
        float rs[4] = {0.f, 0.f, 0.f, 0.f};
#pragma unroll
        for (int j = 0; j < 4; ++j) {
#pragma unroll
            for (int q = 0; q < 4; ++q) {
                float p = __expf(s[j][q] - mrun[q]);
                rs[q] += p;
                Ps[wave * 16 + lkb * 4 + q][j * 16 + lr] = b16(p);
            }
        }
#pragma unroll
        for (int q = 0; q < 4; ++q) {
#pragma unroll
            for (int off = 1; off < 16; off <<= 1)
                rs[q] += __shfl_xor(rs[q], off);
            lrun[q] = lrun[q] * alpha[q] + rs[q];
        }
#pragma unroll
        for (int dj = 0; dj < 4; ++dj)
#pragma unroll
            for (int q = 0; q < 4; ++q) o[dj][q] *= alpha[q];
        // no barrier: Ps rows are wave-private

        short8 pa0 = *reinterpret_cast<const short8*>(&Ps[wave * 16 + lr][lkb * 8]);
        short8 pa1 = *reinterpret_cast<const short8*>(&Ps[wave * 16 + lr][32 + lkb * 8]);
#pragma unroll
        for (int dj = 0; dj < 4; ++dj) {
            short8 vb0 = *reinterpret_cast<const short8*>(&VsT[dj * 16 + lr][lkb * 8]);
            short8 vb1 = *reinterpret_cast<const short8*>(&VsT[dj * 16 + lr][32 + lkb * 8]);
            o[dj] = mfma16(pa0, vb0, o[dj]);
            o[dj] = mfma16(pa1, vb1, o[dj]);
        }
    }

#pragma unroll
    for (int dj = 0; dj < 4; ++dj) {
#pragma unroll
        for (int q = 0; q < 4; ++q) {
            int row = q0 + wave * 16 + lkb * 4 + q;
            int col = dj * 16 + lr;
            float val = o[dj][q] / lrun[q];
            O[baseo + (size_t)row * ldo + col] = b16(val);
        }
    }
}

// ---------------- moving average (k=25, zero-pad, /25) + LayerNorm ----------------
__global__ __launch_bounds__(256) void mavg_ln_kernel(const float* __restrict__ r,
                                                      const float* __restrict__ g,
                                                      const float* __restrict__ be,
                                                      float* __restrict__ out,
                                                      bf16* __restrict__ outb) {
    const int row = blockIdx.x;
    const int b = row >> 11, l = row & 2047;
    const int t = threadIdx.x, c = t * 4;
    const float* base = r + (size_t)b * LSEQ * DMODEL;
    int j0 = l - 12; if (j0 < 0) j0 = 0;
    int j1 = l + 12; if (j1 > LSEQ - 1) j1 = LSEQ - 1;
    float s0 = 0.f, s1 = 0.f, s2 = 0.f, s3 = 0.f;
    for (int j = j0; j <= j1; ++j) {
        float4 v = *reinterpret_cast<const float4*>(&base[(size_t)j * DMODEL + c]);
        s0 += v.x; s1 += v.y; s2 += v.z; s3 += v.w;
    }
    const float kinv = 1.0f / 25.0f;
    float t0 = s0 * kinv, t1 = s1 * kinv, t2 = s2 * kinv, t3 = s3 * kinv;
    float p1 = t0 + t1 + t2 + t3;
    float p2 = t0 * t0 + t1 * t1 + t2 * t2 + t3 * t3;
    const int lane = t & 63, wv = t >> 6;
#pragma unroll
    for (int off = 1; off < 64; off <<= 1) {
        p1 += __shfl_xor(p1, off);
        p2 += __shfl_xor(p2, off);
    }
    __shared__ float red[8];
    if (lane == 0) { red[wv] = p1; red[4 + wv] = p2; }
    __syncthreads();
    p1 = red[0] + red[1] + red[2] + red[3];
    p2 = red[4] + red[5] + red[6] + red[7];
    const float mu  = p1 * (1.0f / 1024.0f);
    const float var = p2 * (1.0f / 1024.0f) - mu * mu;
    const float inv = rsqrtf(var + 1e-5f);
    float4 gg = *reinterpret_cast<const float4*>(&g[c]);
    float4 bb = *reinterpret_cast<const float4*>(&be[c]);
    float o0 = (t0 - mu) * inv * gg.x + bb.x;
    float o1 = (t1 - mu) * inv * gg.y + bb.y;
    float o2 = (t2 - mu) * inv * gg.z + bb.z;
    float o3 = (t3 - mu) * inv * gg.w + bb.w;
    float4 ov; ov.x = o0; ov.y = o1; ov.z = o2; ov.w = o3;
    *reinterpret_cast<float4*>(&out[(size_t)row * DMODEL + c]) = ov;
    if (outb) {
        union { ushort4 u; bf16 hh[4]; } ob;
        ob.hh[0] = b16(o0); ob.hh[1] = b16(o1); ob.hh[2] = b16(o2); ob.hh[3] = b16(o3);
        reinterpret_cast<ushort4*>(outb + (size_t)row * DMODEL)[t] = ob.u;
    }
}

extern "C" void kernel_launch(void* const* d_in, const int* in_sizes, int n_in,
                              void* d_out, int out_size, void* d_ws, size_t ws_size,
                              hipStream_t stream) {
    const float* x   = (const float*)d_in[0];
    const float* Wq  = (const float*)d_in[1];
    const float* bq  = (const float*)d_in[2];
    const float* Wk  = (const float*)d_in[3];
    const float* bk  = (const float*)d_in[4];
    const float* Wv  = (const float*)d_in[5];
    const float* bv  = (const float*)d_in[6];
    const float* Wo  = (const float*)d_in[7];
    const float* bo  = (const float*)d_in[8];
    const float* W1  = (const float*)d_in[9];
    const float* b1  = (const float*)d_in[10];
    const float* W2  = (const float*)d_in[11];
    const float* b2  = (const float*)d_in[12];
    const float* g1  = (const float*)d_in[13];
    const float* be1 = (const float*)d_in[14];
    const float* g2  = (const float*)d_in[15];
    const float* be2 = (const float*)d_in[16];
    float* out = (float*)d_out;
    char* ws = (char*)d_ws;
    const size_t MB = 1u << 20;

    // timeline-overlapped layout (152MB total):
    float* rr   = (float*)(ws + 0);        // 16MB  (steps 5-6, 9-10)
    bf16* xb    = (bf16*)(ws + 0);         //  8MB  (steps 1-2; dead before rr)
    bf16* qkvb  = (bf16*)(ws + 16 * MB);   // 24MB  (2-3)
    bf16* ab    = (bf16*)(ws + 16 * MB);   //  8MB  (6-7; qkvb dead)
    bf16* hb    = (bf16*)(ws + 24 * MB);   // 32MB  (7-8)
    bf16* aob   = (bf16*)(ws + 40 * MB);   //  8MB  (3-4)
    bf16* Wqkvb = (bf16*)(ws + 48 * MB);   //  6MB  (1-2)
    bf16* Wob   = (bf16*)(ws + 54 * MB);   //  2MB  (1-4)
    bf16* W1b   = (bf16*)(ws + 56 * MB);   //  8MB  (1-7)
    bf16* W2b   = (bf16*)(ws + 64 * MB);   //  8MB  (1-8)
    float* P    = (float*)(ws + 72 * MB);  // 64MB  partials
    float* a    = (float*)(ws + 136 * MB); // 16MB  (6-9)
    float* bqkv = (float*)(ws + 136 * MB); // 12KB  (1-2; dead before a)

    // 1. dtype conversions (merged dispatches)
    f2b1_kernel<<<(MROWS * DMODEL / 4) / 256, 256, 0, stream>>>(x, xb, MROWS * DMODEL / 4);
    f2b4_kernel<<<dim3((DMODEL * DMODEL / 4) / 256, 4), 256, 0, stream>>>(
        Wq, Wk, Wv, Wo,
        Wqkvb, Wqkvb + DMODEL * DMODEL, Wqkvb + 2 * DMODEL * DMODEL, Wob,
        DMODEL * DMODEL / 4);
    f2b4_kernel<<<dim3((DFF * DMODEL / 4) / 256, 2), 256, 0, stream>>>(
        W1, W2, nullptr, nullptr, W1b, W2b, nullptr, nullptr, DFF * DMODEL / 4);
    concat3_kernel<<<4, 256, 0, stream>>>(bq, bk, bv, bqkv);

    dim3 blk(256);
    // 2. fused QKV projection -> qkvb [4096][3072]
    gemm_bt<2><<<dim3(32, 24), blk, 0, stream>>>(xb, Wqkvb, bqkv, qkvb,
                                                 MROWS, 3 * DMODEL, DMODEL, DMODEL, DMODEL);
    // 3. attention (banded +-3 tiles)
    attn_kernel<<<dim3(32, 32), blk, 0, stream>>>(qkvb, qkvb + DMODEL, qkvb + 2 * DMODEL,
                                                  aob, 3 * DMODEL, DMODEL);
    // 4. output projection, split-K=2 -> P[0:2]
    gemm_bt<3><<<dim3(32, 8, 2), blk, 0, stream>>>(aob, Wob, nullptr, P,
                                                   MROWS, DMODEL, DMODEL, DMODEL, DMODEL / 2);
    // 5. rr = x + P0 + P1 + bo
    reduce_kernel<2><<<(MROWS * DMODEL / 4) / 256, blk, 0, stream>>>(x, P, bo, rr, MROWS * DMODEL / 4);
    // 6. movavg + LN1
    mavg_ln_kernel<<<MROWS, blk, 0, stream>>>(rr, g1, be1, a, ab);
    // 7. FF1 (GELU, bf16 out)
    gemm_bt<1><<<dim3(32, 32), blk, 0, stream>>>(ab, W1b, b1, hb,
                                                 MROWS, DFF, DMODEL, DMODEL, DMODEL);
    // 8. FF2, split-K=4 -> P[0:4]
    gemm_bt<3><<<dim3(32, 8, 4), blk, 0, stream>>>(hb, W2b, nullptr, P,
                                                   MROWS, DMODEL, DFF, DFF, DFF / 4);
    // 9. rr = a + sum(P) + b2
    reduce_kernel<4><<<(MROWS * DMODEL / 4) / 256, blk, 0, stream>>>(a, P, b2, rr, MROWS * DMODEL / 4);
    // 10. movavg + LN2 -> out
    mavg_ln_kernel<<<MROWS, blk, 0, stream>>>(rr, g2, be2, out, nullptr);
}

// Round 5
// 284.802 us; speedup vs baseline: 2.1058x; 1.2732x over previous
//
#include <hip/hip_runtime.h>
#include <hip/hip_bf16.h>
#include <math.h>

#define DMODEL 1024
#define LSEQ   2048
#define BATCH  2
#define NHEADS 16
#define DHEAD  64
#define DFF    4096
#define MROWS  (BATCH*LSEQ)   // 4096

typedef __attribute__((ext_vector_type(8))) short short8;
typedef __attribute__((ext_vector_type(4))) float f32x4;
using bf16 = __hip_bfloat16;

static __device__ __forceinline__ f32x4 mfma16(short8 a, short8 b, f32x4 c) {
    return __builtin_amdgcn_mfma_f32_16x16x32_bf16(a, b, c, 0, 0, 0);
}

static __device__ __forceinline__ void gload16(const void* g, void* l) {
    __builtin_amdgcn_global_load_lds(
        (const __attribute__((address_space(1))) char*)g,
        (__attribute__((address_space(3))) char*)l, 16, 0, 0);
}

static __device__ __forceinline__ bf16 b16(float v) { return __float2bfloat16(v); }

// ---------------- fp32 -> bf16 conversion (multi-buffer via blockIdx.y) ----------------
__global__ void f2b1_kernel(const float* __restrict__ in, bf16* __restrict__ out, int n4) {
    int i = blockIdx.x * blockDim.x + threadIdx.x;
    if (i >= n4) return;
    float4 v = reinterpret_cast<const float4*>(in)[i];
    union { ushort4 u; bf16 h[4]; } o;
    o.h[0] = b16(v.x); o.h[1] = b16(v.y); o.h[2] = b16(v.z); o.h[3] = b16(v.w);
    reinterpret_cast<ushort4*>(out)[i] = o.u;
}

__global__ void f2b4_kernel(const float* p0, const float* p1, const float* p2, const float* p3,
                            bf16* o0, bf16* o1, bf16* o2, bf16* o3, int n4) {
    const float* in; bf16* out;
    switch (blockIdx.y) {
        case 0: in = p0; out = o0; break;
        case 1: in = p1; out = o1; break;
        case 2: in = p2; out = o2; break;
        default: in = p3; out = o3; break;
    }
    int i = blockIdx.x * blockDim.x + threadIdx.x;
    if (i >= n4) return;
    float4 v = reinterpret_cast<const float4*>(in)[i];
    union { ushort4 u; bf16 h[4]; } o;
    o.h[0] = b16(v.x); o.h[1] = b16(v.y); o.h[2] = b16(v.z); o.h[3] = b16(v.w);
    reinterpret_cast<ushort4*>(out)[i] = o.u;
}

// ---------------- bias concat (bq,bk,bv -> 3072) ----------------
__global__ void concat3_kernel(const float* __restrict__ a, const float* __restrict__ b,
                               const float* __restrict__ c, float* __restrict__ o) {
    int i = blockIdx.x * blockDim.x + threadIdx.x;
    if (i < DMODEL) { o[i] = a[i]; o[DMODEL + i] = b[i]; o[2 * DMODEL + i] = c[i]; }
}

// ---------------- split-K reduce: out = res + sum_s P_s + bias ----------------
template<int S>
__global__ __launch_bounds__(256) void reduce_kernel(const float* __restrict__ res,
                                                     const float* __restrict__ P,
                                                     const float* __restrict__ bias,
                                                     float* __restrict__ out, int n4) {
    int i = blockIdx.x * blockDim.x + threadIdx.x;
    if (i >= n4) return;
    float4 acc = reinterpret_cast<const float4*>(res)[i];
#pragma unroll
    for (int s = 0; s < S; ++s) {
        float4 p = reinterpret_cast<const float4*>(P)[i + (size_t)s * (MROWS * DMODEL / 4)];
        acc.x += p.x; acc.y += p.y; acc.z += p.z; acc.w += p.w;
    }
    float4 bs = reinterpret_cast<const float4*>(bias)[i & (DMODEL / 4 - 1)];
    acc.x += bs.x; acc.y += bs.y; acc.z += bs.z; acc.w += bs.w;
    reinterpret_cast<float4*>(out)[i] = acc;
}

// ---------------- GEMM: C[M,N] = A[M,Ksl]@W[N,Ksl]^T (+bias) ----------------
// 2-phase double-buffered pipeline; operand-swapped MFMA for vectorized epilogue.
// EPI: 0 = fp32+bias, 1 = GELU(tanh approx)+bf16, 2 = bf16+bias,
//      3 = fp32 partial (no bias), blockIdx.z = K-split index
template<int EPI>
__global__ __launch_bounds__(256) void gemm_bt(const bf16* __restrict__ A,
                                               const bf16* __restrict__ W,
                                               const float* __restrict__ bias,
                                               void* __restrict__ Cout,
                                               int M, int N, int lda, int ldw, int K) {
    __shared__ bf16 sm[16384];   // [2 bufs][A 4096 | W 4096] = 32 KB
    const int t    = threadIdx.x;
    const int m0   = blockIdx.x * 128;
    const int n0   = blockIdx.y * 128;
    const int sk   = blockIdx.z;
    const int wave = t >> 6, lane = t & 63;
    const int wr   = (wave >> 1) * 64;
    const int wc   = (wave & 1) * 64;
    const int lr   = lane & 15, lkb = lane >> 4;
    const int srow = t >> 2, scol = (t & 3) * 8;

    const bf16* Ag0 = A + (size_t)(m0 + srow) * lda + (size_t)sk * K + scol;
    const bf16* Ag1 = A + (size_t)(m0 + 64 + srow) * lda + (size_t)sk * K + scol;
    const bf16* Wg0 = W + (size_t)(n0 + srow) * ldw + (size_t)sk * K + scol;
    const bf16* Wg1 = W + (size_t)(n0 + 64 + srow) * ldw + (size_t)sk * K + scol;

    f32x4 acc[4][4];
#pragma unroll
    for (int i = 0; i < 4; ++i)
#pragma unroll
        for (int j = 0; j < 4; ++j)
            acc[i][j] = (f32x4){0.f, 0.f, 0.f, 0.f};

    const int nt = K >> 5;
    auto stage = [&](int buf, int kt) {
        const int off = kt * 32;
        bf16* AsW = sm + buf * 4096 + wave * 512;          // wave-uniform base
        bf16* WsW = sm + 8192 + buf * 4096 + wave * 512;   // HW adds lane*16B
        gload16(Ag0 + off, AsW);
        gload16(Ag1 + off, AsW + 2048);
        gload16(Wg0 + off, WsW);
        gload16(Wg1 + off, WsW + 2048);
    };

    stage(0, 0);
    __syncthreads();                 // vmcnt(0) drain of prologue stage
    int cur = 0;
    for (int kt = 0; kt < nt; ++kt) {
        if (kt + 1 < nt) stage(cur ^ 1, kt + 1);   // overlap issue with compute
        short8 a[4], b[4];
#pragma unroll
        for (int i = 0; i < 4; ++i)
            a[i] = *reinterpret_cast<const short8*>(
                &sm[cur * 4096 + (wr + i * 16 + lr) * 32 + lkb * 8]);
#pragma unroll
        for (int j = 0; j < 4; ++j)
            b[j] = *reinterpret_cast<const short8*>(
                &sm[8192 + cur * 4096 + (wc + j * 16 + lr) * 32 + lkb * 8]);
#pragma unroll
        for (int i = 0; i < 4; ++i)
#pragma unroll
            for (int j = 0; j < 4; ++j)
                acc[i][j] = mfma16(b[j], a[i], acc[i][j]);   // swapped operands
        __syncthreads();             // drains next-tile stage (vmcnt) + lgkm
        cur ^= 1;
    }

    // epilogue: swapped layout -> lane holds M-row (m0+wr+i*16+lr),
    // N-cols (n0+wc+j*16+lkb*4 + 0..3) consecutive
    float* Cp = (float*)Cout + (EPI == 3 ? (size_t)sk * M * N : 0);
#pragma unroll
    for (int i = 0; i < 4; ++i) {
        const int row = m0 + wr + i * 16 + lr;
#pragma unroll
        for (int j = 0; j < 4; ++j) {
            const int col = n0 + wc + j * 16 + lkb * 4;
            f32x4 v = acc[i][j];
            if (EPI != 3) {
                float4 bs = *reinterpret_cast<const float4*>(&bias[col]);
                v[0] += bs.x; v[1] += bs.y; v[2] += bs.z; v[3] += bs.w;
            }
            if (EPI == 0 || EPI == 3) {
                float4 ov; ov.x = v[0]; ov.y = v[1]; ov.z = v[2]; ov.w = v[3];
                *reinterpret_cast<float4*>(&Cp[(size_t)row * N + col]) = ov;
            } else if (EPI == 1) {
                union { ushort4 u; bf16 h[4]; } ob;
#pragma unroll
                for (int q = 0; q < 4; ++q) {
                    float x = v[q];
                    float u2 = x * (1.5957691216f + 0.0713548162f * x * x);
                    float e = __expf(fminf(u2, 60.f));
                    ob.h[q] = b16(x * (e / (e + 1.f)));   // x*sigmoid(2u)
                }
                *reinterpret_cast<ushort4*>(
                    &reinterpret_cast<bf16*>(Cout)[(size_t)row * N + col]) = ob.u;
            } else {
                union { ushort4 u; bf16 h[4]; } ob;
#pragma unroll
                for (int q = 0; q < 4; ++q) ob.h[q] = b16(v[q]);
                *reinterpret_cast<ushort4*>(
                    &reinterpret_cast<bf16*>(Cout)[(size_t)row * N + col]) = ob.u;
            }
        }
    }
}

// ---------------- fused attention (flash-style, bf16 MFMA, banded) ----------------
__global__ __launch_bounds__(256) void attn_kernel(const bf16* __restrict__ Q,
                                                   const bf16* __restrict__ Km,
                                                   const bf16* __restrict__ V,
                                                   bf16* __restrict__ O,
                                                   int ldq, int ldo) {
    __shared__ bf16 Qs[64][72];
    __shared__ bf16 Ks[64][72];
    __shared__ bf16 VsT[64][72];   // transposed V tile: VsT[d][m]
    __shared__ bf16 Ps[64][72];
    const int t    = threadIdx.x;
    const int wave = t >> 6, lane = t & 63;
    const int lr   = lane & 15, lkb = lane >> 4;
    const int qt   = blockIdx.x;
    const int q0   = qt * 64;
    const int b    = blockIdx.y >> 4, h = blockIdx.y & 15;
    const size_t base  = (size_t)b * LSEQ * ldq + (size_t)h * DHEAD;
    const size_t baseo = (size_t)b * LSEQ * ldo + (size_t)h * DHEAD;

#pragma unroll
    for (int p = 0; p < 2; ++p) {
        int idx = t + p * 256;
        int row = idx >> 3, c = (idx & 7) * 8;
        *reinterpret_cast<uint4*>(&Qs[row][c]) =
            *reinterpret_cast<const uint4*>(&Q[base + (size_t)(q0 + row) * ldq + c]);
    }
    __syncthreads();
    short8 qa[2];
    qa[0] = *reinterpret_cast<const short8*>(&Qs[wave * 16 + lr][lkb * 8]);
    qa[1] = *reinterpret_cast<const short8*>(&Qs[wave * 16 + lr][32 + lkb * 8]);

    f32x4 o[4];
#pragma unroll
    for (int dj = 0; dj < 4; ++dj) o[dj] = (f32x4){0.f, 0.f, 0.f, 0.f};
    float mrun[4], lrun[4];
#pragma unroll
    for (int q = 0; q < 4; ++q) { mrun[q] = -1e30f; lrun[q] = 0.f; }

    int kt0 = qt - 3; if (kt0 < 0) kt0 = 0;
    int kt1 = qt + 3; if (kt1 > LSEQ / 64 - 1) kt1 = LSEQ / 64 - 1;

    for (int kt = kt0; kt <= kt1; ++kt) {
        const int k0 = kt * 64;
        __syncthreads();
#pragma unroll
        for (int p = 0; p < 2; ++p) {
            int idx = t + p * 256;
            int row = idx >> 3, c = (idx & 7) * 8;
            *reinterpret_cast<uint4*>(&Ks[row][c]) =
                *reinterpret_cast<const uint4*>(&Km[base + (size_t)(k0 + row) * ldq + c]);
        }
        {
            const int vl = lane, vw = wave;
#pragma unroll
            for (int p = 0; p < 2; ++p) {
                int c = vw * 8 + p * 32;
                union { uint4 u; bf16 hh[8]; } tv;
                tv.u = *reinterpret_cast<const uint4*>(&V[base + (size_t)(k0 + vl) * ldq + c]);
#pragma unroll
                for (int e = 0; e < 8; ++e) VsT[c + e][vl] = tv.hh[e];
            }
        }
        __syncthreads();

        f32x4 s[4];
#pragma unroll
        for (int j = 0; j < 4; ++j) {
            short8 kb0 = *reinterpret_cast<const short8*>(&Ks[j * 16 + lr][lkb * 8]);
            short8 kb1 = *reinterpret_cast<const short8*>(&Ks[j * 16 + lr][32 + lkb * 8]);
            f32x4 z = (f32x4){0.f, 0.f, 0.f, 0.f};
            z = mfma16(qa[0], kb0, z);
            z = mfma16(qa[1], kb1, z);
            s[j] = z;
        }
        float mx[4];
#pragma unroll
        for (int q = 0; q < 4; ++q) mx[q] = -1e30f;
#pragma unroll
        for (int j = 0; j < 4; ++j) {
            int cm = k0 + j * 16 + lr;
#pragma unroll
            for (int q = 0; q < 4; ++q) {
                int rq = q0 + wave * 16 + lkb * 4 + q;
                float sv = s[j][q] * 0.125f - 0.1f * fabsf((float)(rq - cm));
                s[j][q] = sv;
                mx[q] = fmaxf(mx[q], sv);
            }
        }
#pragma unroll
        for (int q = 0; q < 4; ++q) {
#pragma unroll
            for (int off = 1; off < 16; off <<= 1)
                mx[q] = fmaxf(mx[q], __shfl_xor(mx[q], off));
        }
        float alpha[4];
#pragma unroll
        for (int q = 0; q < 4; ++q) {
            float mnew = fmaxf(mrun[q], mx[q]);
            alpha[q] = __expf(mrun[q] - mnew);
            mrun[q] = mnew;
        }
        float rs[4] = {0.f, 0.f, 0.f, 0.f};
#pragma unroll
        for (int j = 0; j < 4; ++j) {
#pragma unroll
            for (int q = 0; q < 4; ++q) {
                float p = __expf(s[j][q] - mrun[q]);
                rs[q] += p;
                Ps[wave * 16 + lkb * 4 + q][j * 16 + lr] = b16(p);
            }
        }
#pragma unroll
        for (int q = 0; q < 4; ++q) {
#pragma unroll
            for (int off = 1; off < 16; off <<= 1)
                rs[q] += __shfl_xor(rs[q], off);
            lrun[q] = lrun[q] * alpha[q] + rs[q];
        }
#pragma unroll
        for (int dj = 0; dj < 4; ++dj)
#pragma unroll
            for (int q = 0; q < 4; ++q) o[dj][q] *= alpha[q];
        // no barrier: Ps rows are wave-private

        short8 pa0 = *reinterpret_cast<const short8*>(&Ps[wave * 16 + lr][lkb * 8]);
        short8 pa1 = *reinterpret_cast<const short8*>(&Ps[wave * 16 + lr][32 + lkb * 8]);
#pragma unroll
        for (int dj = 0; dj < 4; ++dj) {
            short8 vb0 = *reinterpret_cast<const short8*>(&VsT[dj * 16 + lr][lkb * 8]);
            short8 vb1 = *reinterpret_cast<const short8*>(&VsT[dj * 16 + lr][32 + lkb * 8]);
            o[dj] = mfma16(pa0, vb0, o[dj]);
            o[dj] = mfma16(pa1, vb1, o[dj]);
        }
    }

#pragma unroll
    for (int dj = 0; dj < 4; ++dj) {
#pragma unroll
        for (int q = 0; q < 4; ++q) {
            int row = q0 + wave * 16 + lkb * 4 + q;
            int col = dj * 16 + lr;
            float val = o[dj][q] / lrun[q];
            O[baseo + (size_t)row * ldo + col] = b16(val);
        }
    }
}

// ---------------- moving average (k=25, zero-pad, /25) + LayerNorm ----------------
// XCD-aware swizzle: each XCD owns a contiguous 512-row chunk so the 24 neighbor
// re-reads hit that XCD's private L2 (2MB working set < 4MB L2).
__global__ __launch_bounds__(256) void mavg_ln_kernel(const float* __restrict__ r,
                                                      const float* __restrict__ g,
                                                      const float* __restrict__ be,
                                                      float* __restrict__ out,
                                                      bf16* __restrict__ outb) {
    const int row = (blockIdx.x & 7) * (MROWS / 8) + (blockIdx.x >> 3);  // bijective: 4096%8==0
    const int b = row >> 11, l = row & 2047;
    const int t = threadIdx.x, c = t * 4;
    const float* base = r + (size_t)b * LSEQ * DMODEL;
    int j0 = l - 12; if (j0 < 0) j0 = 0;
    int j1 = l + 12; if (j1 > LSEQ - 1) j1 = LSEQ - 1;
    float s0 = 0.f, s1 = 0.f, s2 = 0.f, s3 = 0.f;
    for (int j = j0; j <= j1; ++j) {
        float4 v = *reinterpret_cast<const float4*>(&base[(size_t)j * DMODEL + c]);
        s0 += v.x; s1 += v.y; s2 += v.z; s3 += v.w;
    }
    const float kinv = 1.0f / 25.0f;
    float t0 = s0 * kinv, t1 = s1 * kinv, t2 = s2 * kinv, t3 = s3 * kinv;
    float p1 = t0 + t1 + t2 + t3;
    float p2 = t0 * t0 + t1 * t1 + t2 * t2 + t3 * t3;
    const int lane = t & 63, wv = t >> 6;
#pragma unroll
    for (int off = 1; off < 64; off <<= 1) {
        p1 += __shfl_xor(p1, off);
        p2 += __shfl_xor(p2, off);
    }
    __shared__ float red[8];
    if (lane == 0) { red[wv] = p1; red[4 + wv] = p2; }
    __syncthreads();
    p1 = red[0] + red[1] + red[2] + red[3];
    p2 = red[4] + red[5] + red[6] + red[7];
    const float mu  = p1 * (1.0f / 1024.0f);
    const float var = p2 * (1.0f / 1024.0f) - mu * mu;
    const float inv = rsqrtf(var + 1e-5f);
    float4 gg = *reinterpret_cast<const float4*>(&g[c]);
    float4 bb = *reinterpret_cast<const float4*>(&be[c]);
    float o0 = (t0 - mu) * inv * gg.x + bb.x;
    float o1 = (t1 - mu) * inv * gg.y + bb.y;
    float o2 = (t2 - mu) * inv * gg.z + bb.z;
    float o3 = (t3 - mu) * inv * gg.w + bb.w;
    float4 ov; ov.x = o0; ov.y = o1; ov.z = o2; ov.w = o3;
    *reinterpret_cast<float4*>(&out[(size_t)row * DMODEL + c]) = ov;
    if (outb) {
        union { ushort4 u; bf16 hh[4]; } ob;
        ob.hh[0] = b16(o0); ob.hh[1] = b16(o1); ob.hh[2] = b16(o2); ob.hh[3] = b16(o3);
        reinterpret_cast<ushort4*>(outb + (size_t)row * DMODEL)[t] = ob.u;
    }
}

extern "C" void kernel_launch(void* const* d_in, const int* in_sizes, int n_in,
                              void* d_out, int out_size, void* d_ws, size_t ws_size,
                              hipStream_t stream) {
    const float* x   = (const float*)d_in[0];
    const float* Wq  = (const float*)d_in[1];
    const float* bq  = (const float*)d_in[2];
    const float* Wk  = (const float*)d_in[3];
    const float* bk  = (const float*)d_in[4];
    const float* Wv  = (const float*)d_in[5];
    const float* bv  = (const float*)d_in[6];
    const float* Wo  = (const float*)d_in[7];
    const float* bo  = (const float*)d_in[8];
    const float* W1  = (const float*)d_in[9];
    const float* b1  = (const float*)d_in[10];
    const float* W2  = (const float*)d_in[11];
    const float* b2  = (const float*)d_in[12];
    const float* g1  = (const float*)d_in[13];
    const float* be1 = (const float*)d_in[14];
    const float* g2  = (const float*)d_in[15];
    const float* be2 = (const float*)d_in[16];
    float* out = (float*)d_out;
    char* ws = (char*)d_ws;
    const size_t MB = 1u << 20;

    // timeline-overlapped layout (152MB total):
    float* rr   = (float*)(ws + 0);        // 16MB  (steps 5-6, 9-10)
    bf16* xb    = (bf16*)(ws + 0);         //  8MB  (steps 1-2; dead before rr)
    bf16* qkvb  = (bf16*)(ws + 16 * MB);   // 24MB  (2-3)
    bf16* ab    = (bf16*)(ws + 16 * MB);   //  8MB  (6-7; qkvb dead)
    bf16* hb    = (bf16*)(ws + 24 * MB);   // 32MB  (7-8)
    bf16* aob   = (bf16*)(ws + 40 * MB);   //  8MB  (3-4)
    bf16* Wqkvb = (bf16*)(ws + 48 * MB);   //  6MB  (1-2)
    bf16* Wob   = (bf16*)(ws + 54 * MB);   //  2MB  (1-4)
    bf16* W1b   = (bf16*)(ws + 56 * MB);   //  8MB  (1-7)
    bf16* W2b   = (bf16*)(ws + 64 * MB);   //  8MB  (1-8)
    float* P    = (float*)(ws + 72 * MB);  // 64MB  partials
    float* a    = (float*)(ws + 136 * MB); // 16MB  (6-9)
    float* bqkv = (float*)(ws + 136 * MB); // 12KB  (1-2; dead before a)

    // 1. dtype conversions (merged dispatches)
    f2b1_kernel<<<(MROWS * DMODEL / 4) / 256, 256, 0, stream>>>(x, xb, MROWS * DMODEL / 4);
    f2b4_kernel<<<dim3((DMODEL * DMODEL / 4) / 256, 4), 256, 0, stream>>>(
        Wq, Wk, Wv, Wo,
        Wqkvb, Wqkvb + DMODEL * DMODEL, Wqkvb + 2 * DMODEL * DMODEL, Wob,
        DMODEL * DMODEL / 4);
    f2b4_kernel<<<dim3((DFF * DMODEL / 4) / 256, 2), 256, 0, stream>>>(
        W1, W2, nullptr, nullptr, W1b, W2b, nullptr, nullptr, DFF * DMODEL / 4);
    concat3_kernel<<<4, 256, 0, stream>>>(bq, bk, bv, bqkv);

    dim3 blk(256);
    // 2. fused QKV projection -> qkvb [4096][3072]
    gemm_bt<2><<<dim3(32, 24), blk, 0, stream>>>(xb, Wqkvb, bqkv, qkvb,
                                                 MROWS, 3 * DMODEL, DMODEL, DMODEL, DMODEL);
    // 3. attention (banded +-3 tiles)
    attn_kernel<<<dim3(32, 32), blk, 0, stream>>>(qkvb, qkvb + DMODEL, qkvb + 2 * DMODEL,
                                                  aob, 3 * DMODEL, DMODEL);
    // 4. output projection, split-K=2 -> P[0:2]
    gemm_bt<3><<<dim3(32, 8, 2), blk, 0, stream>>>(aob, Wob, nullptr, P,
                                                   MROWS, DMODEL, DMODEL, DMODEL, DMODEL / 2);
    // 5. rr = x + P0 + P1 + bo
    reduce_kernel<2><<<(MROWS * DMODEL / 4) / 256, blk, 0, stream>>>(x, P, bo, rr, MROWS * DMODEL / 4);
    // 6. movavg + LN1
    mavg_ln_kernel<<<MROWS, blk, 0, stream>>>(rr, g1, be1, a, ab);
    // 7. FF1 (GELU, bf16 out)
    gemm_bt<1><<<dim3(32, 32), blk, 0, stream>>>(ab, W1b, b1, hb,
                                                 MROWS, DFF, DMODEL, DMODEL, DMODEL);
    // 8. FF2, split-K=4 -> P[0:4]
    gemm_bt<3><<<dim3(32, 8, 4), blk, 0, stream>>>(hb, W2b, nullptr, P,
                                                   MROWS, DMODEL, DFF, DFF, DFF / 4);
    // 9. rr = a + sum(P) + b2
    reduce_kernel<4><<<(MROWS * DMODEL / 4) / 256, blk, 0, stream>>>(a, P, b2, rr, MROWS * DMODEL / 4);
    // 10. movavg + LN2 -> out
    mavg_ln_kernel<<<MROWS, blk, 0, stream>>>(rr, g2, be2, out, nullptr);
}